// Round 3
// baseline (2800.282 us; speedup 1.0000x reference)
//
#include <hip/hip_runtime.h>
#include <hip/hip_bf16.h>

// ---------------------------------------------------------------------------
// HyenaPositioning forward: B=8, L=4096, IN=3, H=512, DEPTH=8, FH=64, OUT=2
// Pipeline per depth: LN -> bf16 MFMA GEMM (proj 3H) -> depthwise conv3 (+T)
//  -> radix-4 FFT circular conv (packed 2 batches/complex FFT) -> gate (+T)
//  -> bf16 MFMA GEMM + residual.
// WS budget ~242 MB: per-depth weight transposes, bf16 us/filtered, filt
// overlaid on the ust region (disjoint lifetimes within a depth iteration).
// ---------------------------------------------------------------------------

typedef short bf16x8 __attribute__((ext_vector_type(8)));
typedef float f32x4 __attribute__((ext_vector_type(4)));

__device__ __forceinline__ float bf2f(short s) {
    return __uint_as_float(((unsigned)(unsigned short)s) << 16);
}
__device__ __forceinline__ short f2bf(float f) {
    __hip_bfloat16 h = __float2bfloat16(f);
    return *reinterpret_cast<short*>(&h);
}
__device__ __forceinline__ float gelu_exact(float x) {
    return 0.5f * x * (1.0f + erff(x * 0.70710678118654752f));
}
__device__ __forceinline__ float sigmoidf_(float x) {
    return 1.0f / (1.0f + expf(-x));
}
__device__ __forceinline__ float2 cmul(float2 a, float2 b) {
    return make_float2(a.x*b.x - a.y*b.y, a.x*b.y + a.y*b.x);
}
__device__ __forceinline__ float2 cmulc(float2 a, float2 b) {  // a * conj(b)
    return make_float2(a.x*b.x + a.y*b.y, a.y*b.x - a.x*b.y);
}

__device__ __forceinline__ void gload_lds16(const void* gsrc, void* ldsdst) {
    __builtin_amdgcn_global_load_lds(
        (const __attribute__((address_space(1))) void*)gsrc,
        (__attribute__((address_space(3))) void*)ldsdst, 16, 0, 0);
}

// ---------------------------------------------------------------------------
// Embed: h = x@in_w + in_b + pe + edge_emb[edge_ids[b]]
// ---------------------------------------------------------------------------
__global__ __launch_bounds__(256)
void embed_kernel(const float* __restrict__ x, const int* __restrict__ eids,
                  const float* __restrict__ in_w, const float* __restrict__ in_b,
                  const float* __restrict__ eemb, float* __restrict__ h)
{
    const int bl = blockIdx.x;           // b*4096 + l
    const int b  = bl >> 12;
    const int l  = bl & 4095;
    const float x0 = x[bl*3 + 0], x1 = x[bl*3 + 1], x2 = x[bl*3 + 2];
    const int e = eids[b];
    #pragma unroll
    for (int i = 0; i < 2; ++i) {
        int col = threadIdx.x + 256*i;
        int k = col >> 1;
        // div[k] = exp(-(2k) * ln(1e4)/512)
        float dv = expf(-0.03597789207803197f * (float)k);
        float ang = (float)l * dv;
        float pe = (col & 1) ? cosf(ang) : sinf(ang);
        float val = x0*in_w[col] + x1*in_w[512 + col] + x2*in_w[1024 + col]
                  + in_b[col] + pe + eemb[e*512 + col];
        h[(size_t)bl*512 + col] = val;
    }
}

// ---------------------------------------------------------------------------
// LayerNorm over H=512: one wave per row, output bf16
// ---------------------------------------------------------------------------
__global__ __launch_bounds__(256)
void ln_kernel(const float* __restrict__ hsrc, const float* __restrict__ g,
               const float* __restrict__ bta, short* __restrict__ out)
{
    const int m = blockIdx.x * 4 + (threadIdx.x >> 6);
    const int lane = threadIdx.x & 63;
    const float4* hp = (const float4*)(hsrc + (size_t)m * 512);
    float4 v0 = hp[lane*2], v1 = hp[lane*2 + 1];
    float xs[8] = {v0.x, v0.y, v0.z, v0.w, v1.x, v1.y, v1.z, v1.w};
    float s = 0.f, sq = 0.f;
    #pragma unroll
    for (int i = 0; i < 8; ++i) { s += xs[i]; sq += xs[i]*xs[i]; }
    #pragma unroll
    for (int o = 32; o > 0; o >>= 1) { s += __shfl_xor(s, o); sq += __shfl_xor(sq, o); }
    float mean = s * (1.f/512.f);
    float var  = sq * (1.f/512.f) - mean*mean;
    float rs = rsqrtf(var + 1e-5f);
    short res[8];
    #pragma unroll
    for (int i = 0; i < 8; ++i) {
        int col = lane*8 + i;
        res[i] = f2bf((xs[i] - mean) * rs * g[col] + bta[col]);
    }
    *(bf16x8*)(out + (size_t)m*512 + lane*8) = *(bf16x8*)res;
}

// ---------------------------------------------------------------------------
// bf16 MFMA GEMM, 128x128 tile, BK=64, 4 waves, global_load_lds staging with
// XOR-8-element swizzle (2-way max bank aliasing on ds_read_b128).
// A [M][K] bf16 row-major, Bt [N][K] bf16 (pre-transposed).
// EPI 0: bf16 store (+bias). 1: f32 residual add (+bias). 2: gelu->bf16.
// ---------------------------------------------------------------------------
template<int EPI>
__global__ __launch_bounds__(256)
void gemm_bf16(const short* __restrict__ A, const short* __restrict__ Bt,
               const float* __restrict__ bias, short* __restrict__ Cb,
               float* __restrict__ Cres, int N, int K)
{
    __shared__ __align__(16) short As[128 * 64];
    __shared__ __align__(16) short Bs[128 * 64];
    const int tid = threadIdx.x;
    const int w = tid >> 6, lane = tid & 63;
    const int m0 = blockIdx.x * 128, n0 = blockIdx.y * 128;
    const int wm = w >> 1, wn = w & 1;
    const int lane15 = lane & 15, lhi = lane >> 4;

    f32x4 acc[4][4];
    #pragma unroll
    for (int i = 0; i < 4; ++i)
        #pragma unroll
        for (int j = 0; j < 4; ++j) acc[i][j] = (f32x4){0.f, 0.f, 0.f, 0.f};

    for (int k0 = 0; k0 < K; k0 += 64) {
        #pragma unroll
        for (int i = 0; i < 4; ++i) {
            int row = 32*w + 8*i + (lane >> 3);
            int kch = (lane & 7) ^ (row & 7);
            gload_lds16(A + (size_t)(m0 + row) * K + k0 + kch*8, &As[(32*w + 8*i) * 64]);
        }
        #pragma unroll
        for (int i = 0; i < 4; ++i) {
            int row = 32*w + 8*i + (lane >> 3);
            int kch = (lane & 7) ^ (row & 7);
            gload_lds16(Bt + (size_t)(n0 + row) * K + k0 + kch*8, &Bs[(32*w + 8*i) * 64]);
        }
        __syncthreads();
        #pragma unroll
        for (int kk = 0; kk < 64; kk += 32) {
            bf16x8 af[4], bfr[4];
            const int kb = kk + lhi * 8;
            #pragma unroll
            for (int mi = 0; mi < 4; ++mi) {
                int row = wm*64 + mi*16 + lane15;
                af[mi] = *(const bf16x8*)&As[(row*64 + kb) ^ ((row & 7) << 3)];
            }
            #pragma unroll
            for (int ni = 0; ni < 4; ++ni) {
                int row = wn*64 + ni*16 + lane15;
                bfr[ni] = *(const bf16x8*)&Bs[(row*64 + kb) ^ ((row & 7) << 3)];
            }
            #pragma unroll
            for (int mi = 0; mi < 4; ++mi)
                #pragma unroll
                for (int ni = 0; ni < 4; ++ni)
                    acc[mi][ni] = __builtin_amdgcn_mfma_f32_16x16x32_bf16(
                        af[mi], bfr[ni], acc[mi][ni], 0, 0, 0);
        }
        __syncthreads();
    }
    // epilogue: D row=(lane>>4)*4+reg, col=lane&15 (HW-verified mapping)
    #pragma unroll
    for (int mi = 0; mi < 4; ++mi) {
        #pragma unroll
        for (int ni = 0; ni < 4; ++ni) {
            int gcol = n0 + wn*64 + ni*16 + lane15;
            float bv = bias[gcol];
            #pragma unroll
            for (int r = 0; r < 4; ++r) {
                int grow = m0 + wm*64 + mi*16 + lhi*4 + r;
                float val = acc[mi][ni][r] + bv;
                if (EPI == 0) {
                    Cb[(size_t)grow * N + gcol] = f2bf(val);
                } else if (EPI == 1) {
                    float* p = Cres + (size_t)grow * N + gcol;
                    *p += val;
                } else {
                    Cb[(size_t)grow * N + gcol] = f2bf(gelu_exact(val));
                }
            }
        }
    }
}

// ---------------------------------------------------------------------------
// Filter MLP: f1=gelu(t*fw1+fb1); f2=gelu(f1@fw2+fb2); filt=f2@fw3+fb3
// One block = 64 seq positions x 128 output channels; writes filt_t[h][l] f32.
// ---------------------------------------------------------------------------
__global__ __launch_bounds__(256)
void mlp_kernel(const float* __restrict__ fw1, const float* __restrict__ fb1,
                const float* __restrict__ fw2, const float* __restrict__ fb2,
                const float* __restrict__ fw3, const float* __restrict__ fb3,
                float* __restrict__ filt_t)
{
    __shared__ float F1[64][65];
    __shared__ float F2[64][65];
    __shared__ float FO[64][129];
    const int lt = blockIdx.x, ns = blockIdx.y;
    const int l0 = lt * 64, nb = ns * 128;
    const int tid = threadIdx.x;
    for (int i = tid; i < 4096; i += 256) {
        int l = i >> 6, j = i & 63;
        float tv = (float)(l0 + l) * (1.0f / 4095.0f);
        F1[l][j] = gelu_exact(tv * fw1[j] + fb1[j]);
    }
    __syncthreads();
    {
        int j = tid & 63, lb = tid >> 6;
        for (int li = 0; li < 16; ++li) {
            int l = lb*16 + li;
            float sum = fb2[j];
            #pragma unroll
            for (int k = 0; k < 64; ++k) sum += F1[l][k] * fw2[k*64 + j];
            F2[l][j] = gelu_exact(sum);
        }
    }
    __syncthreads();
    {
        const int nn = tid & 127;
        const int lofs = tid >> 7;
        for (int jj = 0; jj < 32; ++jj) {
            int l = lofs + 2*jj;
            float sum = fb3[nb + nn];
            #pragma unroll
            for (int k = 0; k < 64; ++k) sum += F2[l][k] * fw3[k*512 + nb + nn];
            FO[l][nn] = sum;
        }
    }
    __syncthreads();
    for (int i = tid; i < 8192; i += 256) {
        int nn = i >> 6, l = i & 63;
        filt_t[(size_t)(nb + nn) * 4096 + l0 + l] = FO[l][nn];
    }
}

// ---------------------------------------------------------------------------
// Depthwise conv3 (pad=1) fused with transpose to (B,H,L) layout, bf16 out.
// ---------------------------------------------------------------------------
__global__ __launch_bounds__(256)
void convT_kernel(const short* __restrict__ proj, const float* __restrict__ cw,
                  const float* __restrict__ cb, short* __restrict__ ust)
{
    __shared__ float U[66][65];
    __shared__ float O[64][65];
    const int lt = blockIdx.x, ht = blockIdx.y, b = blockIdx.z;
    const int l0 = lt * 64, h0 = ht * 64;
    const int tid = threadIdx.x;
    const int c63 = tid & 63, r4 = tid >> 6;
    for (int r = r4; r < 66; r += 4) {
        int l = l0 - 1 + r;
        float v = 0.f;
        if (l >= 0 && l < 4096)
            v = bf2f(proj[((size_t)(b*4096 + l)) * 1536 + 512 + h0 + c63]);
        U[r][c63] = v;
    }
    __syncthreads();
    const int hcol = h0 + c63;
    const float c0 = cw[hcol*3], c1 = cw[hcol*3+1], c2 = cw[hcol*3+2];
    const float cbv = cb[hcol];
    #pragma unroll
    for (int j = 0; j < 16; ++j) {
        int r = r4 + 4*j;    // output row within tile
        O[r][c63] = U[r][c63]*c0 + U[r+1][c63]*c1 + U[r+2][c63]*c2 + cbv;
    }
    __syncthreads();
    for (int j = 0; j < 16; ++j) {
        int hh = r4 + 4*j;
        ust[((size_t)(b*512 + h0 + hh)) * 4096 + l0 + c63] = f2bf(O[c63][hh]);
    }
}

// ---------------------------------------------------------------------------
// Radix-4 FFT (4096 pts, 6 stages), in-LDS, padded indexing (i + i/16).
// MODE 0: real f32 filt row -> full complex spectrum (digit-reversed order).
// MODE 1: pack 2 batches (bf16) as re/im, DIF fwd, multiply by F (fused into
//         inverse stage 0, unity twiddles), inverse stages, scale 1/N, bf16.
// ---------------------------------------------------------------------------
#define FIDX(i) ((i) + ((i) >> 4))

template<int MODE>
__global__ __launch_bounds__(256)
void fft_kernel(const float* __restrict__ rin_f, const short* __restrict__ rin_h,
                const float2* __restrict__ Fh, short* __restrict__ rout_h,
                float2* __restrict__ Fout, const float2* __restrict__ tw)
{
    __shared__ float2 S[4096 + 256];
    const int tid = threadIdx.x;
    const int hh = blockIdx.x;
    if (MODE == 0) {
        const float* src = rin_f + (size_t)hh * 4096;
        for (int i = tid; i < 4096; i += 256) S[FIDX(i)] = make_float2(src[i], 0.f);
    } else {
        const int b0 = blockIdx.y * 2, b1 = b0 + 1;
        const short* s0 = rin_h + ((size_t)b0 * 512 + hh) * 4096;
        const short* s1 = rin_h + ((size_t)b1 * 512 + hh) * 4096;
        for (int i = tid; i < 4096; i += 256)
            S[FIDX(i)] = make_float2(bf2f(s0[i]), bf2f(s1[i]));
    }
    __syncthreads();
    // forward DIF radix-4: natural in -> digit-reversed out
    #pragma unroll
    for (int s = 0; s < 6; ++s) {
        const int lq = 10 - 2*s;
        const int q = 1 << lq;
        const int tf = 1 << (2*s);
        for (int bfy = tid; bfy < 1024; bfy += 256) {
            const int j = bfy & (q - 1);
            const int base = ((bfy >> lq) << (lq + 2)) + j;
            float2 a = S[FIDX(base)];
            float2 b = S[FIDX(base + q)];
            float2 c = S[FIDX(base + 2*q)];
            float2 d = S[FIDX(base + 3*q)];
            float2 t0 = make_float2(a.x + c.x, a.y + c.y);
            float2 t1 = make_float2(a.x - c.x, a.y - c.y);
            float2 t2 = make_float2(b.x + d.x, b.y + d.y);
            float2 t3 = make_float2(b.x - d.x, b.y - d.y);
            float2 o0 = make_float2(t0.x + t2.x, t0.y + t2.y);
            float2 p1 = make_float2(t1.x + t3.y, t1.y - t3.x);   // t1 - i*t3
            float2 p2 = make_float2(t0.x - t2.x, t0.y - t2.y);
            float2 p3 = make_float2(t1.x - t3.y, t1.y + t3.x);   // t1 + i*t3
            S[FIDX(base)]       = o0;
            S[FIDX(base + q)]   = cmul(p1, tw[j * tf]);
            S[FIDX(base + 2*q)] = cmul(p2, tw[2 * j * tf]);
            S[FIDX(base + 3*q)] = cmul(p3, tw[3 * j * tf]);
        }
        __syncthreads();
    }
    if (MODE == 0) {
        float2* dst = Fout + (size_t)hh * 4096;
        for (int i = tid; i < 4096; i += 256) dst[i] = S[FIDX(i)];
        return;
    }
    // inverse = exact algebraic inverse of each fwd stage, reverse order;
    // spectrum multiply fused where twiddles are unity (s==0). Net gain 4^6,
    // removed by the 1/4096 output scale.
    const float2* F = Fh + (size_t)hh * 4096;
    #pragma unroll
    for (int s = 0; s < 6; ++s) {
        const int q = 1 << (2*s);
        const int tf = 1 << (10 - 2*s);
        for (int bfy = tid; bfy < 1024; bfy += 256) {
            const int j = bfy & (q - 1);
            const int base = ((bfy >> (2*s)) << (2*s + 2)) + j;
            float2 u0 = S[FIDX(base)];
            float2 u1 = S[FIDX(base + q)];
            float2 u2 = S[FIDX(base + 2*q)];
            float2 u3 = S[FIDX(base + 3*q)];
            if (s == 0) {
                u0 = cmul(u0, F[base]);     u1 = cmul(u1, F[base + 1]);
                u2 = cmul(u2, F[base + 2]); u3 = cmul(u3, F[base + 3]);
            } else {
                u1 = cmulc(u1, tw[j * tf]);
                u2 = cmulc(u2, tw[2 * j * tf]);
                u3 = cmulc(u3, tw[3 * j * tf]);
            }
            float2 pp = make_float2(u0.x + u2.x, u0.y + u2.y);
            float2 mm = make_float2(u0.x - u2.x, u0.y - u2.y);
            float2 rr = make_float2(u1.x + u3.x, u1.y + u3.y);
            float2 tt = make_float2(u1.x - u3.x, u1.y - u3.y);
            S[FIDX(base)]       = make_float2(pp.x + rr.x, pp.y + rr.y);
            S[FIDX(base + q)]   = make_float2(mm.x - tt.y, mm.y + tt.x);  // m + i*t
            S[FIDX(base + 2*q)] = make_float2(pp.x - rr.x, pp.y - rr.y);
            S[FIDX(base + 3*q)] = make_float2(mm.x + tt.y, mm.y - tt.x);  // m - i*t
        }
        __syncthreads();
    }
    const int b0 = blockIdx.y * 2, b1 = b0 + 1;
    short* d0 = rout_h + ((size_t)b0 * 512 + hh) * 4096;
    short* d1 = rout_h + ((size_t)b1 * 512 + hh) * 4096;
    const float inv = 1.0f / 4096.0f;
    for (int i = tid; i < 4096; i += 256) {
        float2 v = S[FIDX(i)];
        d0[i] = f2bf(v.x * inv);
        d1[i] = f2bf(v.y * inv);
    }
}

// ---------------------------------------------------------------------------
// Gate: out = v * filtered * sigmoid(z); transpose back (B,H,L)->(B,L,H), bf16
// ---------------------------------------------------------------------------
__global__ __launch_bounds__(256)
void gateT_kernel(const short* __restrict__ ft, const short* __restrict__ proj,
                  short* __restrict__ gated)
{
    __shared__ float Fd[64][65];
    const int lt = blockIdx.x, ht = blockIdx.y, b = blockIdx.z;
    const int l0 = lt * 64, h0 = ht * 64;
    const int tid = threadIdx.x, c63 = tid & 63, r4 = tid >> 6;
    for (int j = 0; j < 16; ++j) {
        int hh = r4 + 4*j;
        Fd[hh][c63] = bf2f(ft[((size_t)(b*512 + h0 + hh)) * 4096 + l0 + c63]);
    }
    __syncthreads();
    for (int j = 0; j < 16; ++j) {
        int l = l0 + r4 + 4*j;
        size_t mrow = (size_t)(b*4096 + l) * 1536;
        float v = bf2f(proj[mrow + h0 + c63]);
        float z = bf2f(proj[mrow + 1024 + h0 + c63]);
        float f = Fd[c63][r4 + 4*j];
        gated[(size_t)(b*4096 + l) * 512 + h0 + c63] = f2bf(v * f * sigmoidf_(z));
    }
}

// ---------------------------------------------------------------------------
// Weight transpose + f32->bf16: in [R][C] -> out [C][R]
// ---------------------------------------------------------------------------
__global__ __launch_bounds__(256)
void transpose_cvt(const float* __restrict__ in, short* __restrict__ out, int R, int C)
{
    __shared__ float T[32][33];
    const float* ip = in;
    short* op = out;
    int tx = threadIdx.x & 31, ty = threadIdx.x >> 5;
    int r0 = blockIdx.y * 32, c0 = blockIdx.x * 32;
    for (int j = 0; j < 4; ++j)
        T[ty + 8*j][tx] = ip[(size_t)(r0 + ty + 8*j) * C + c0 + tx];
    __syncthreads();
    for (int j = 0; j < 4; ++j)
        op[(size_t)(c0 + ty + 8*j) * R + r0 + tx] = f2bf(T[tx][ty + 8*j]);
}

__global__ void twiddle_kernel(float2* tw)
{
    int k = blockIdx.x * 256 + threadIdx.x;
    if (k < 4096) {
        float ang = -(float)(6.283185307179586 / 4096.0) * (float)k;
        tw[k] = make_float2(cosf(ang), sinf(ang));
    }
}

// ---------------------------------------------------------------------------
// Head: out[m][0..1] = g2[m]@hw2 + hb2 (one wave per row)
// ---------------------------------------------------------------------------
__global__ __launch_bounds__(256)
void head_kernel(const short* __restrict__ g2, const float* __restrict__ hw2,
                 const float* __restrict__ hb2, float* __restrict__ out)
{
    const int m = blockIdx.x * 4 + (threadIdx.x >> 6);
    const int lane = threadIdx.x & 63;
    const short* row = g2 + (size_t)m * 256;
    float a0 = 0.f, a1 = 0.f;
    #pragma unroll
    for (int i = 0; i < 4; ++i) {
        int k = lane*4 + i;
        float gv = bf2f(row[k]);
        a0 += gv * hw2[2*k];
        a1 += gv * hw2[2*k + 1];
    }
    #pragma unroll
    for (int o = 32; o > 0; o >>= 1) { a0 += __shfl_xor(a0, o); a1 += __shfl_xor(a1, o); }
    if (lane == 0) {
        out[(size_t)m*2]     = a0 + hb2[0];
        out[(size_t)m*2 + 1] = a1 + hb2[1];
    }
}

// ---------------------------------------------------------------------------
extern "C" void kernel_launch(void* const* d_in, const int* in_sizes, int n_in,
                              void* d_out, int out_size, void* d_ws, size_t ws_size,
                              hipStream_t stream)
{
    const float* x      = (const float*)d_in[0];
    const int*   eids   = (const int*)d_in[1];
    const float* in_w   = (const float*)d_in[2];
    const float* in_b   = (const float*)d_in[3];
    const float* eemb   = (const float*)d_in[4];
    const float* ln_g   = (const float*)d_in[5];
    const float* ln_b   = (const float*)d_in[6];
    const float* fw1    = (const float*)d_in[7];
    const float* fb1    = (const float*)d_in[8];
    const float* fw2    = (const float*)d_in[9];
    const float* fb2    = (const float*)d_in[10];
    const float* fw3    = (const float*)d_in[11];
    const float* fb3    = (const float*)d_in[12];
    const float* cw     = (const float*)d_in[13];
    const float* cb     = (const float*)d_in[14];
    const float* win_w  = (const float*)d_in[15];
    const float* win_b  = (const float*)d_in[16];
    const float* wout_w = (const float*)d_in[17];
    const float* wout_b = (const float*)d_in[18];
    const float* fln_g  = (const float*)d_in[19];
    const float* fln_b  = (const float*)d_in[20];
    const float* hw1    = (const float*)d_in[21];
    const float* hb1    = (const float*)d_in[22];
    const float* hw2    = (const float*)d_in[23];
    const float* hb2    = (const float*)d_in[24];
    float* out = (float*)d_out;

    // ---- workspace layout (~242 MB) ----
    char* p = (char*)d_ws;
    auto alloc = [&](size_t bytes) { char* r = p; p += (bytes + 255) & ~(size_t)255; return r; };
    float2* tw    = (float2*)alloc((size_t)4096 * sizeof(float2));      // 32 KB
    short*  winT  = (short*)alloc((size_t)1536 * 512 * 2);              // 1.6 MB (per depth)
    short*  woutT = (short*)alloc((size_t)512 * 512 * 2);               // 0.5 MB (per depth)
    short*  hw1T  = (short*)alloc((size_t)256 * 512 * 2);               // 0.26 MB
    float*  h     = (float*)alloc((size_t)32768 * 512 * 4);             // 64 MB
    short*  hn    = (short*)alloc((size_t)32768 * 512 * 2);             // 32 MB (also: gated)
    short*  proj  = (short*)alloc((size_t)32768 * 1536 * 2);            // 96 MB (also: g2)
    short*  ust   = (short*)alloc((size_t)8 * 512 * 4096 * 2);          // 32 MB us/filtered bf16
    float*  filt  = (float*)ust;   // overlay: filt (8 MB f32) dead before convT writes ust
    float2* Fh    = (float2*)alloc((size_t)512 * 4096 * sizeof(float2)); // 16 MB

    twiddle_kernel<<<16, 256, 0, stream>>>(tw);
    transpose_cvt<<<dim3(256/32, 512/32), 256, 0, stream>>>(hw1, hw1T, 512, 256);
    embed_kernel<<<32768, 256, 0, stream>>>(x, eids, in_w, in_b, eemb, h);

    for (int d = 0; d < 8; ++d) {
        transpose_cvt<<<dim3(1536/32, 512/32), 256, 0, stream>>>(
            win_w + (size_t)d*512*1536, winT, 512, 1536);
        transpose_cvt<<<dim3(512/32, 512/32), 256, 0, stream>>>(
            wout_w + (size_t)d*512*512, woutT, 512, 512);
        mlp_kernel<<<dim3(64, 4), 256, 0, stream>>>(
            fw1 + d*64, fb1 + d*64, fw2 + (size_t)d*64*64, fb2 + d*64,
            fw3 + (size_t)d*64*512, fb3 + d*512, filt);
        fft_kernel<0><<<512, 256, 0, stream>>>(filt, nullptr, nullptr, nullptr, Fh, tw);
        ln_kernel<<<8192, 256, 0, stream>>>(h, ln_g + d*512, ln_b + d*512, hn);
        gemm_bf16<0><<<dim3(256, 12), 256, 0, stream>>>(
            hn, winT, win_b + d*1536, proj, nullptr, 1536, 512);
        convT_kernel<<<dim3(64, 8, 8), 256, 0, stream>>>(
            proj, cw + (size_t)d*512*3, cb + d*512, ust);
        fft_kernel<1><<<dim3(512, 4), 256, 0, stream>>>(nullptr, ust, Fh, ust, nullptr, tw);
        gateT_kernel<<<dim3(64, 8, 8), 256, 0, stream>>>(ust, proj, hn);
        gemm_bf16<1><<<dim3(256, 4), 256, 0, stream>>>(
            hn, woutT, wout_b + d*512, nullptr, h, 512, 512);
    }

    ln_kernel<<<8192, 256, 0, stream>>>(h, fln_g, fln_b, hn);
    gemm_bf16<2><<<dim3(256, 2), 256, 0, stream>>>(hn, hw1T, hb1, proj, nullptr, 256, 512);
    head_kernel<<<8192, 256, 0, stream>>>(proj, hw2, hb2, out);
}

// Round 9
// 2770.613 us; speedup vs baseline: 1.0107x; 1.0107x over previous
//
#include <hip/hip_runtime.h>
#include <hip/hip_bf16.h>

// ---------------------------------------------------------------------------
// HyenaPositioning forward: B=8, L=4096, IN=3, H=512, DEPTH=8, FH=64, OUT=2
// Per depth: LN -> gemm_u (u^T transposed out) + gemm_vz (fused sigmoid gate)
//  -> fft<1> (conv3 fused into load, circular FFT conv, 2 batches packed)
//  -> gateT (g * filtered, transpose back) -> gemm residual.
// proj (3H) is never materialized. WS ~193 MB.
// ---------------------------------------------------------------------------

typedef short bf16x8 __attribute__((ext_vector_type(8)));
typedef float f32x4 __attribute__((ext_vector_type(4)));

__device__ __forceinline__ float bf2f(short s) {
    return __uint_as_float(((unsigned)(unsigned short)s) << 16);
}
__device__ __forceinline__ short f2bf(float f) {
    __hip_bfloat16 h = __float2bfloat16(f);
    return *reinterpret_cast<short*>(&h);
}
__device__ __forceinline__ float gelu_exact(float x) {
    return 0.5f * x * (1.0f + erff(x * 0.70710678118654752f));
}
__device__ __forceinline__ float sigmoidf_(float x) {
    return 1.0f / (1.0f + expf(-x));
}
__device__ __forceinline__ float2 cmul(float2 a, float2 b) {
    return make_float2(a.x*b.x - a.y*b.y, a.x*b.y + a.y*b.x);
}
__device__ __forceinline__ float2 cmulc(float2 a, float2 b) {  // a * conj(b)
    return make_float2(a.x*b.x + a.y*b.y, a.y*b.x - a.x*b.y);
}

__device__ __forceinline__ void gload_lds16(const void* gsrc, void* ldsdst) {
    __builtin_amdgcn_global_load_lds(
        (const __attribute__((address_space(1))) void*)gsrc,
        (__attribute__((address_space(3))) void*)ldsdst, 16, 0, 0);
}

// ---------------------------------------------------------------------------
// Embed: h = x@in_w + in_b + pe + edge_emb[edge_ids[b]]
// ---------------------------------------------------------------------------
__global__ __launch_bounds__(256)
void embed_kernel(const float* __restrict__ x, const int* __restrict__ eids,
                  const float* __restrict__ in_w, const float* __restrict__ in_b,
                  const float* __restrict__ eemb, float* __restrict__ h)
{
    const int bl = blockIdx.x;           // b*4096 + l
    const int b  = bl >> 12;
    const int l  = bl & 4095;
    const float x0 = x[bl*3 + 0], x1 = x[bl*3 + 1], x2 = x[bl*3 + 2];
    const int e = eids[b];
    #pragma unroll
    for (int i = 0; i < 2; ++i) {
        int col = threadIdx.x + 256*i;
        int k = col >> 1;
        float dv = expf(-0.03597789207803197f * (float)k);
        float ang = (float)l * dv;
        float pe = (col & 1) ? cosf(ang) : sinf(ang);
        float val = x0*in_w[col] + x1*in_w[512 + col] + x2*in_w[1024 + col]
                  + in_b[col] + pe + eemb[e*512 + col];
        h[(size_t)bl*512 + col] = val;
    }
}

// ---------------------------------------------------------------------------
// LayerNorm over H=512: one wave per row, output bf16
// ---------------------------------------------------------------------------
__global__ __launch_bounds__(256)
void ln_kernel(const float* __restrict__ hsrc, const float* __restrict__ g,
               const float* __restrict__ bta, short* __restrict__ out)
{
    const int m = blockIdx.x * 4 + (threadIdx.x >> 6);
    const int lane = threadIdx.x & 63;
    const float4* hp = (const float4*)(hsrc + (size_t)m * 512);
    float4 v0 = hp[lane*2], v1 = hp[lane*2 + 1];
    float xs[8] = {v0.x, v0.y, v0.z, v0.w, v1.x, v1.y, v1.z, v1.w};
    float s = 0.f, sq = 0.f;
    #pragma unroll
    for (int i = 0; i < 8; ++i) { s += xs[i]; sq += xs[i]*xs[i]; }
    #pragma unroll
    for (int o = 32; o > 0; o >>= 1) { s += __shfl_xor(s, o); sq += __shfl_xor(sq, o); }
    float mean = s * (1.f/512.f);
    float var  = sq * (1.f/512.f) - mean*mean;
    float rs = rsqrtf(var + 1e-5f);
    short res[8];
    #pragma unroll
    for (int i = 0; i < 8; ++i) {
        int col = lane*8 + i;
        res[i] = f2bf((xs[i] - mean) * rs * g[col] + bta[col]);
    }
    *(bf16x8*)(out + (size_t)m*512 + lane*8) = *(bf16x8*)res;
}

// ---------------------------------------------------------------------------
// gemm_bf16: generic A[M][K] x Bt[N][K]; EPI 1: f32 residual add (+bias),
// EPI 2: gelu->bf16. 128x128 tile, BK=64, 4 waves, global_load_lds + XOR-8
// swizzle, 16x16x32 bf16 MFMA.
// ---------------------------------------------------------------------------
template<int EPI>
__global__ __launch_bounds__(256)
void gemm_bf16(const short* __restrict__ A, const short* __restrict__ Bt,
               const float* __restrict__ bias, short* __restrict__ Cb,
               float* __restrict__ Cres, int N, int K)
{
    __shared__ __align__(16) short As[128 * 64];
    __shared__ __align__(16) short Bs[128 * 64];
    const int tid = threadIdx.x;
    const int w = tid >> 6, lane = tid & 63;
    const int m0 = blockIdx.x * 128, n0 = blockIdx.y * 128;
    const int wm = w >> 1, wn = w & 1;
    const int lane15 = lane & 15, lhi = lane >> 4;

    f32x4 acc[4][4];
    #pragma unroll
    for (int i = 0; i < 4; ++i)
        #pragma unroll
        for (int j = 0; j < 4; ++j) acc[i][j] = (f32x4){0.f, 0.f, 0.f, 0.f};

    for (int k0 = 0; k0 < K; k0 += 64) {
        #pragma unroll
        for (int i = 0; i < 4; ++i) {
            int row = 32*w + 8*i + (lane >> 3);
            int kch = (lane & 7) ^ (row & 7);
            gload_lds16(A + (size_t)(m0 + row) * K + k0 + kch*8, &As[(32*w + 8*i) * 64]);
        }
        #pragma unroll
        for (int i = 0; i < 4; ++i) {
            int row = 32*w + 8*i + (lane >> 3);
            int kch = (lane & 7) ^ (row & 7);
            gload_lds16(Bt + (size_t)(n0 + row) * K + k0 + kch*8, &Bs[(32*w + 8*i) * 64]);
        }
        __syncthreads();
        #pragma unroll
        for (int kk = 0; kk < 64; kk += 32) {
            bf16x8 af[4], bfr[4];
            const int kb = kk + lhi * 8;
            #pragma unroll
            for (int mi = 0; mi < 4; ++mi) {
                int row = wm*64 + mi*16 + lane15;
                af[mi] = *(const bf16x8*)&As[(row*64 + kb) ^ ((row & 7) << 3)];
            }
            #pragma unroll
            for (int ni = 0; ni < 4; ++ni) {
                int row = wn*64 + ni*16 + lane15;
                bfr[ni] = *(const bf16x8*)&Bs[(row*64 + kb) ^ ((row & 7) << 3)];
            }
            #pragma unroll
            for (int mi = 0; mi < 4; ++mi)
                #pragma unroll
                for (int ni = 0; ni < 4; ++ni)
                    acc[mi][ni] = __builtin_amdgcn_mfma_f32_16x16x32_bf16(
                        af[mi], bfr[ni], acc[mi][ni], 0, 0, 0);
        }
        __syncthreads();
    }
    #pragma unroll
    for (int mi = 0; mi < 4; ++mi) {
        #pragma unroll
        for (int ni = 0; ni < 4; ++ni) {
            int gcol = n0 + wn*64 + ni*16 + lane15;
            float bv = bias[gcol];
            #pragma unroll
            for (int r = 0; r < 4; ++r) {
                int grow = m0 + wm*64 + mi*16 + lhi*4 + r;
                float val = acc[mi][ni][r] + bv;
                if (EPI == 1) {
                    float* p = Cres + (size_t)grow * N + gcol;
                    *p += val;
                } else {
                    Cb[(size_t)grow * N + gcol] = f2bf(gelu_exact(val));
                }
            }
        }
    }
}

// ---------------------------------------------------------------------------
// gemm_u: A=hn[32768][512] x Bt=winT u-rows [512][512] -> u^T (B,H,L) bf16.
// Epilogue transposes the 128x128 tile in LDS (reusing As/Bs) with an XOR
// swizzle on l, then stores 256B row segments of u^T.
// ---------------------------------------------------------------------------
__global__ __launch_bounds__(256)
void gemm_u(const short* __restrict__ A, const short* __restrict__ Bt,
            const float* __restrict__ bias, short* __restrict__ ut)
{
    __shared__ __align__(16) short smem[128 * 128];   // As | Bs, then T
    short* As = smem;
    short* Bs = smem + 128*64;
    const int tid = threadIdx.x;
    const int w = tid >> 6, lane = tid & 63;
    const int m0 = blockIdx.x * 128, n0 = blockIdx.y * 128;
    const int wm = w >> 1, wn = w & 1;
    const int lane15 = lane & 15, lhi = lane >> 4;
    const int K = 512;

    f32x4 acc[4][4];
    #pragma unroll
    for (int i = 0; i < 4; ++i)
        #pragma unroll
        for (int j = 0; j < 4; ++j) acc[i][j] = (f32x4){0.f, 0.f, 0.f, 0.f};

    for (int k0 = 0; k0 < K; k0 += 64) {
        #pragma unroll
        for (int i = 0; i < 4; ++i) {
            int row = 32*w + 8*i + (lane >> 3);
            int kch = (lane & 7) ^ (row & 7);
            gload_lds16(A + (size_t)(m0 + row) * K + k0 + kch*8, &As[(32*w + 8*i) * 64]);
        }
        #pragma unroll
        for (int i = 0; i < 4; ++i) {
            int row = 32*w + 8*i + (lane >> 3);
            int kch = (lane & 7) ^ (row & 7);
            gload_lds16(Bt + (size_t)(n0 + row) * K + k0 + kch*8, &Bs[(32*w + 8*i) * 64]);
        }
        __syncthreads();
        #pragma unroll
        for (int kk = 0; kk < 64; kk += 32) {
            bf16x8 af[4], bfr[4];
            const int kb = kk + lhi * 8;
            #pragma unroll
            for (int mi = 0; mi < 4; ++mi) {
                int row = wm*64 + mi*16 + lane15;
                af[mi] = *(const bf16x8*)&As[(row*64 + kb) ^ ((row & 7) << 3)];
            }
            #pragma unroll
            for (int ni = 0; ni < 4; ++ni) {
                int row = wn*64 + ni*16 + lane15;
                bfr[ni] = *(const bf16x8*)&Bs[(row*64 + kb) ^ ((row & 7) << 3)];
            }
            #pragma unroll
            for (int mi = 0; mi < 4; ++mi)
                #pragma unroll
                for (int ni = 0; ni < 4; ++ni)
                    acc[mi][ni] = __builtin_amdgcn_mfma_f32_16x16x32_bf16(
                        af[mi], bfr[ni], acc[mi][ni], 0, 0, 0);
        }
        __syncthreads();
    }
    // T[h][l]: index = h*128 + (l ^ ((h&7)<<3))
    #pragma unroll
    for (int mi = 0; mi < 4; ++mi) {
        #pragma unroll
        for (int ni = 0; ni < 4; ++ni) {
            int hcol = wn*64 + ni*16 + lane15;
            float bv = bias[n0 + hcol];
            #pragma unroll
            for (int r = 0; r < 4; ++r) {
                int bl = wm*64 + mi*16 + lhi*4 + r;
                smem[hcol*128 + (bl ^ ((hcol & 7) << 3))] = f2bf(acc[mi][ni][r] + bv);
            }
        }
    }
    __syncthreads();
    const int b = m0 >> 12, l0 = m0 & 4095;
    #pragma unroll
    for (int p = 0; p < 8; ++p) {
        int hh = p*16 + (tid >> 4);
        int lbase = (tid & 15) * 8;
        bf16x8 v = *(const bf16x8*)&smem[hh*128 + (lbase ^ ((hh & 7) << 3))];
        *(bf16x8*)(ut + ((size_t)(b*512 + n0 + hh))*4096 + l0 + lbase) = v;
    }
}

// ---------------------------------------------------------------------------
// gemm_vz: computes v-tile (winT rows n) and z-tile (winT rows 1024+n),
// writes g = (v+bv)*sigmoid(z+bz) bf16 [32768][512].
// ---------------------------------------------------------------------------
__global__ __launch_bounds__(256)
void gemm_vz(const short* __restrict__ A, const short* __restrict__ BtW,
             const float* __restrict__ biasW, short* __restrict__ G)
{
    __shared__ __align__(16) short As[128 * 64];
    __shared__ __align__(16) short Bv[128 * 64];
    __shared__ __align__(16) short Bz[128 * 64];
    const int tid = threadIdx.x;
    const int w = tid >> 6, lane = tid & 63;
    const int m0 = blockIdx.x * 128, n0 = blockIdx.y * 128;
    const int wm = w >> 1, wn = w & 1;
    const int lane15 = lane & 15, lhi = lane >> 4;
    const int K = 512;
    const short* BtZ = BtW + (size_t)1024 * 512;

    f32x4 av[4][4], az[4][4];
    #pragma unroll
    for (int i = 0; i < 4; ++i)
        #pragma unroll
        for (int j = 0; j < 4; ++j) {
            av[i][j] = (f32x4){0.f, 0.f, 0.f, 0.f};
            az[i][j] = (f32x4){0.f, 0.f, 0.f, 0.f};
        }

    for (int k0 = 0; k0 < K; k0 += 64) {
        #pragma unroll
        for (int i = 0; i < 4; ++i) {
            int row = 32*w + 8*i + (lane >> 3);
            int kch = (lane & 7) ^ (row & 7);
            gload_lds16(A + (size_t)(m0 + row) * K + k0 + kch*8, &As[(32*w + 8*i) * 64]);
        }
        #pragma unroll
        for (int i = 0; i < 4; ++i) {
            int row = 32*w + 8*i + (lane >> 3);
            int kch = (lane & 7) ^ (row & 7);
            gload_lds16(BtW + (size_t)(n0 + row) * K + k0 + kch*8, &Bv[(32*w + 8*i) * 64]);
        }
        #pragma unroll
        for (int i = 0; i < 4; ++i) {
            int row = 32*w + 8*i + (lane >> 3);
            int kch = (lane & 7) ^ (row & 7);
            gload_lds16(BtZ + (size_t)(n0 + row) * K + k0 + kch*8, &Bz[(32*w + 8*i) * 64]);
        }
        __syncthreads();
        #pragma unroll
        for (int kk = 0; kk < 64; kk += 32) {
            bf16x8 af[4], bfv[4], bfz[4];
            const int kb = kk + lhi * 8;
            #pragma unroll
            for (int mi = 0; mi < 4; ++mi) {
                int row = wm*64 + mi*16 + lane15;
                af[mi] = *(const bf16x8*)&As[(row*64 + kb) ^ ((row & 7) << 3)];
            }
            #pragma unroll
            for (int ni = 0; ni < 4; ++ni) {
                int row = wn*64 + ni*16 + lane15;
                int idx = (row*64 + kb) ^ ((row & 7) << 3);
                bfv[ni] = *(const bf16x8*)&Bv[idx];
                bfz[ni] = *(const bf16x8*)&Bz[idx];
            }
            #pragma unroll
            for (int mi = 0; mi < 4; ++mi)
                #pragma unroll
                for (int ni = 0; ni < 4; ++ni) {
                    av[mi][ni] = __builtin_amdgcn_mfma_f32_16x16x32_bf16(
                        af[mi], bfv[ni], av[mi][ni], 0, 0, 0);
                    az[mi][ni] = __builtin_amdgcn_mfma_f32_16x16x32_bf16(
                        af[mi], bfz[ni], az[mi][ni], 0, 0, 0);
                }
        }
        __syncthreads();
    }
    #pragma unroll
    for (int mi = 0; mi < 4; ++mi) {
        #pragma unroll
        for (int ni = 0; ni < 4; ++ni) {
            int gcol = n0 + wn*64 + ni*16 + lane15;
            float bvv = biasW[gcol];
            float bzz = biasW[1024 + gcol];
            #pragma unroll
            for (int r = 0; r < 4; ++r) {
                int grow = m0 + wm*64 + mi*16 + lhi*4 + r;
                float vv = av[mi][ni][r] + bvv;
                float zz = az[mi][ni][r] + bzz;
                G[(size_t)grow * 512 + gcol] = f2bf(vv * sigmoidf_(zz));
            }
        }
    }
}

// ---------------------------------------------------------------------------
// Filter MLP: writes filt_t[h][l] f32 (512 x 4096)
// ---------------------------------------------------------------------------
__global__ __launch_bounds__(256)
void mlp_kernel(const float* __restrict__ fw1, const float* __restrict__ fb1,
                const float* __restrict__ fw2, const float* __restrict__ fb2,
                const float* __restrict__ fw3, const float* __restrict__ fb3,
                float* __restrict__ filt_t)
{
    __shared__ float F1[64][65];
    __shared__ float F2[64][65];
    __shared__ float FO[64][129];
    const int lt = blockIdx.x, ns = blockIdx.y;
    const int l0 = lt * 64, nb = ns * 128;
    const int tid = threadIdx.x;
    for (int i = tid; i < 4096; i += 256) {
        int l = i >> 6, j = i & 63;
        float tv = (float)(l0 + l) * (1.0f / 4095.0f);
        F1[l][j] = gelu_exact(tv * fw1[j] + fb1[j]);
    }
    __syncthreads();
    {
        int j = tid & 63, lb = tid >> 6;
        for (int li = 0; li < 16; ++li) {
            int l = lb*16 + li;
            float sum = fb2[j];
            #pragma unroll
            for (int k = 0; k < 64; ++k) sum += F1[l][k] * fw2[k*64 + j];
            F2[l][j] = gelu_exact(sum);
        }
    }
    __syncthreads();
    {
        const int nn = tid & 127;
        const int lofs = tid >> 7;
        for (int jj = 0; jj < 32; ++jj) {
            int l = lofs + 2*jj;
            float sum = fb3[nb + nn];
            #pragma unroll
            for (int k = 0; k < 64; ++k) sum += F2[l][k] * fw3[k*512 + nb + nn];
            FO[l][nn] = sum;
        }
    }
    __syncthreads();
    for (int i = tid; i < 8192; i += 256) {
        int nn = i >> 6, l = i & 63;
        filt_t[(size_t)(nb + nn) * 4096 + l0 + l] = FO[l][nn];
    }
}

// ---------------------------------------------------------------------------
// Radix-4 FFT (4096 pts), in-LDS, padded indexing.
// MODE 0: real f32 filt row -> spectrum (digit-reversed) to Fout.
// MODE 1: load u^T bf16 (2 batches packed re/im), depthwise conv3 in LDS,
//         fwd FFT, multiply by Fh (fused in inverse stage 0), inverse,
//         write filtered bf16 (in place over u^T).
// ---------------------------------------------------------------------------
#define FIDX(i) ((i) + ((i) >> 4))

template<int MODE>
__global__ __launch_bounds__(256)
void fft_kernel(const float* __restrict__ rin_f, const short* __restrict__ rin_h,
                const float2* __restrict__ Fh, short* __restrict__ rout_h,
                float2* __restrict__ Fout, const float2* __restrict__ tw,
                const float* __restrict__ cw3, const float* __restrict__ cbv)
{
    __shared__ float2 S[4096 + 256];
    const int tid = threadIdx.x;
    const int hh = blockIdx.x;
    if (MODE == 0) {
        const float* src = rin_f + (size_t)hh * 4096;
        for (int i = tid; i < 4096; i += 256) S[FIDX(i)] = make_float2(src[i], 0.f);
        __syncthreads();
    } else {
        const int b0 = blockIdx.y * 2, b1 = b0 + 1;
        const short* s0 = rin_h + ((size_t)b0 * 512 + hh) * 4096;
        const short* s1 = rin_h + ((size_t)b1 * 512 + hh) * 4096;
        for (int i = tid; i < 4096; i += 256)
            S[FIDX(i)] = make_float2(bf2f(s0[i]), bf2f(s1[i]));
        __syncthreads();
        // depthwise conv3, pad=1 (applies to both packed batches)
        const float c0 = cw3[hh*3 + 0], c1 = cw3[hh*3 + 1], c2 = cw3[hh*3 + 2];
        const float cb = cbv[hh];
        float2 r[16];
        #pragma unroll
        for (int k = 0; k < 16; ++k) {
            int i = tid + 256*k;
            float2 um = (i == 0)    ? make_float2(0.f, 0.f) : S[FIDX(i-1)];
            float2 uc = S[FIDX(i)];
            float2 up = (i == 4095) ? make_float2(0.f, 0.f) : S[FIDX(i+1)];
            r[k] = make_float2(um.x*c0 + uc.x*c1 + up.x*c2 + cb,
                               um.y*c0 + uc.y*c1 + up.y*c2 + cb);
        }
        __syncthreads();
        #pragma unroll
        for (int k = 0; k < 16; ++k) S[FIDX(tid + 256*k)] = r[k];
        __syncthreads();
    }
    // forward DIF radix-4: natural in -> digit-reversed out
    #pragma unroll
    for (int s = 0; s < 6; ++s) {
        const int lq = 10 - 2*s;
        const int q = 1 << lq;
        const int tf = 1 << (2*s);
        for (int bfy = tid; bfy < 1024; bfy += 256) {
            const int j = bfy & (q - 1);
            const int base = ((bfy >> lq) << (lq + 2)) + j;
            float2 a = S[FIDX(base)];
            float2 b = S[FIDX(base + q)];
            float2 c = S[FIDX(base + 2*q)];
            float2 d = S[FIDX(base + 3*q)];
            float2 t0 = make_float2(a.x + c.x, a.y + c.y);
            float2 t1 = make_float2(a.x - c.x, a.y - c.y);
            float2 t2 = make_float2(b.x + d.x, b.y + d.y);
            float2 t3 = make_float2(b.x - d.x, b.y - d.y);
            float2 o0 = make_float2(t0.x + t2.x, t0.y + t2.y);
            float2 p1 = make_float2(t1.x + t3.y, t1.y - t3.x);   // t1 - i*t3
            float2 p2 = make_float2(t0.x - t2.x, t0.y - t2.y);
            float2 p3 = make_float2(t1.x - t3.y, t1.y + t3.x);   // t1 + i*t3
            S[FIDX(base)]       = o0;
            S[FIDX(base + q)]   = cmul(p1, tw[j * tf]);
            S[FIDX(base + 2*q)] = cmul(p2, tw[2 * j * tf]);
            S[FIDX(base + 3*q)] = cmul(p3, tw[3 * j * tf]);
        }
        __syncthreads();
    }
    if (MODE == 0) {
        float2* dst = Fout + (size_t)hh * 4096;
        for (int i = tid; i < 4096; i += 256) dst[i] = S[FIDX(i)];
        return;
    }
    // inverse stages (exact algebraic inverse), spectrum multiply fused at s=0
    const float2* F = Fh + (size_t)hh * 4096;
    #pragma unroll
    for (int s = 0; s < 6; ++s) {
        const int q = 1 << (2*s);
        const int tf = 1 << (10 - 2*s);
        for (int bfy = tid; bfy < 1024; bfy += 256) {
            const int j = bfy & (q - 1);
            const int base = ((bfy >> (2*s)) << (2*s + 2)) + j;
            float2 u0 = S[FIDX(base)];
            float2 u1 = S[FIDX(base + q)];
            float2 u2 = S[FIDX(base + 2*q)];
            float2 u3 = S[FIDX(base + 3*q)];
            if (s == 0) {
                u0 = cmul(u0, F[base]);     u1 = cmul(u1, F[base + 1]);
                u2 = cmul(u2, F[base + 2]); u3 = cmul(u3, F[base + 3]);
            } else {
                u1 = cmulc(u1, tw[j * tf]);
                u2 = cmulc(u2, tw[2 * j * tf]);
                u3 = cmulc(u3, tw[3 * j * tf]);
            }
            float2 pp = make_float2(u0.x + u2.x, u0.y + u2.y);
            float2 mm = make_float2(u0.x - u2.x, u0.y - u2.y);
            float2 rr = make_float2(u1.x + u3.x, u1.y + u3.y);
            float2 tt = make_float2(u1.x - u3.x, u1.y - u3.y);
            S[FIDX(base)]       = make_float2(pp.x + rr.x, pp.y + rr.y);
            S[FIDX(base + q)]   = make_float2(mm.x - tt.y, mm.y + tt.x);
            S[FIDX(base + 2*q)] = make_float2(pp.x - rr.x, pp.y - rr.y);
            S[FIDX(base + 3*q)] = make_float2(mm.x + tt.y, mm.y - tt.x);
        }
        __syncthreads();
    }
    const int b0 = blockIdx.y * 2, b1 = b0 + 1;
    short* d0 = rout_h + ((size_t)b0 * 512 + hh) * 4096;
    short* d1 = rout_h + ((size_t)b1 * 512 + hh) * 4096;
    const float inv = 1.0f / 4096.0f;
    for (int i = tid; i < 4096; i += 256) {
        float2 v = S[FIDX(i)];
        d0[i] = f2bf(v.x * inv);
        d1[i] = f2bf(v.y * inv);
    }
}

// ---------------------------------------------------------------------------
// Gate: gated = g * filtered; transpose filtered (B,H,L)->(B,L,H), bf16
// ---------------------------------------------------------------------------
__global__ __launch_bounds__(256)
void gateT_kernel(const short* __restrict__ ft, const short* __restrict__ g,
                  short* __restrict__ gated)
{
    __shared__ float Fd[64][65];
    const int lt = blockIdx.x, ht = blockIdx.y, b = blockIdx.z;
    const int l0 = lt * 64, h0 = ht * 64;
    const int tid = threadIdx.x, c63 = tid & 63, r4 = tid >> 6;
    for (int j = 0; j < 16; ++j) {
        int hh = r4 + 4*j;
        Fd[hh][c63] = bf2f(ft[((size_t)(b*512 + h0 + hh)) * 4096 + l0 + c63]);
    }
    __syncthreads();
    for (int j = 0; j < 16; ++j) {
        int l = l0 + r4 + 4*j;
        size_t row = (size_t)(b*4096 + l) * 512;
        float gv = bf2f(g[row + h0 + c63]);
        float f = Fd[c63][r4 + 4*j];
        gated[row + h0 + c63] = f2bf(gv * f);
    }
}

// ---------------------------------------------------------------------------
// Weight transpose + f32->bf16: in [R][C] -> out [C][R], z = depth slice
// ---------------------------------------------------------------------------
__global__ __launch_bounds__(256)
void transpose_cvt(const float* __restrict__ in, short* __restrict__ out, int R, int C)
{
    __shared__ float T[32][33];
    const size_t off = (size_t)blockIdx.z * R * C;
    const float* ip = in + off;
    short* op = out + off;
    int tx = threadIdx.x & 31, ty = threadIdx.x >> 5;
    int r0 = blockIdx.y * 32, c0 = blockIdx.x * 32;
    for (int j = 0; j < 4; ++j)
        T[ty + 8*j][tx] = ip[(size_t)(r0 + ty + 8*j) * C + c0 + tx];
    __syncthreads();
    for (int j = 0; j < 4; ++j)
        op[(size_t)(c0 + ty + 8*j) * R + r0 + tx] = f2bf(T[tx][ty + 8*j]);
}

__global__ void twiddle_kernel(float2* tw)
{
    int k = blockIdx.x * 256 + threadIdx.x;
    if (k < 4096) {
        float ang = -(float)(6.283185307179586 / 4096.0) * (float)k;
        tw[k] = make_float2(cosf(ang), sinf(ang));
    }
}

// ---------------------------------------------------------------------------
// Head: out[m][0..1] = g2[m]@hw2 + hb2 (one wave per row)
// ---------------------------------------------------------------------------
__global__ __launch_bounds__(256)
void head_kernel(const short* __restrict__ g2, const float* __restrict__ hw2,
                 const float* __restrict__ hb2, float* __restrict__ out)
{
    const int m = blockIdx.x * 4 + (threadIdx.x >> 6);
    const int lane = threadIdx.x & 63;
    const short* row = g2 + (size_t)m * 256;
    float a0 = 0.f, a1 = 0.f;
    #pragma unroll
    for (int i = 0; i < 4; ++i) {
        int k = lane*4 + i;
        float gv = bf2f(row[k]);
        a0 += gv * hw2[2*k];
        a1 += gv * hw2[2*k + 1];
    }
    #pragma unroll
    for (int o = 32; o > 0; o >>= 1) { a0 += __shfl_xor(a0, o); a1 += __shfl_xor(a1, o); }
    if (lane == 0) {
        out[(size_t)m*2]     = a0 + hb2[0];
        out[(size_t)m*2 + 1] = a1 + hb2[1];
    }
}

// ---------------------------------------------------------------------------
extern "C" void kernel_launch(void* const* d_in, const int* in_sizes, int n_in,
                              void* d_out, int out_size, void* d_ws, size_t ws_size,
                              hipStream_t stream)
{
    const float* x      = (const float*)d_in[0];
    const int*   eids   = (const int*)d_in[1];
    const float* in_w   = (const float*)d_in[2];
    const float* in_b   = (const float*)d_in[3];
    const float* eemb   = (const float*)d_in[4];
    const float* ln_g   = (const float*)d_in[5];
    const float* ln_b   = (const float*)d_in[6];
    const float* fw1    = (const float*)d_in[7];
    const float* fb1    = (const float*)d_in[8];
    const float* fw2    = (const float*)d_in[9];
    const float* fb2    = (const float*)d_in[10];
    const float* fw3    = (const float*)d_in[11];
    const float* fb3    = (const float*)d_in[12];
    const float* cw     = (const float*)d_in[13];
    const float* cb     = (const float*)d_in[14];
    const float* win_w  = (const float*)d_in[15];
    const float* win_b  = (const float*)d_in[16];
    const float* wout_w = (const float*)d_in[17];
    const float* wout_b = (const float*)d_in[18];
    const float* fln_g  = (const float*)d_in[19];
    const float* fln_b  = (const float*)d_in[20];
    const float* hw1    = (const float*)d_in[21];
    const float* hb1    = (const float*)d_in[22];
    const float* hw2    = (const float*)d_in[23];
    const float* hb2    = (const float*)d_in[24];
    float* out = (float*)d_out;

    // ---- workspace layout (~193 MB) ----
    char* p = (char*)d_ws;
    auto alloc = [&](size_t bytes) { char* r = p; p += (bytes + 255) & ~(size_t)255; return r; };
    float2* tw     = (float2*)alloc((size_t)4096 * sizeof(float2));          // 32 KB
    short*  winT8  = (short*)alloc((size_t)8 * 1536 * 512 * 2);              // 12.6 MB
    short*  woutT8 = (short*)alloc((size_t)8 * 512 * 512 * 2);               // 4.2 MB
    short*  hw1T   = (short*)alloc((size_t)256 * 512 * 2);                   // 0.26 MB
    float*  h      = (float*)alloc((size_t)32768 * 512 * 4);                 // 64 MB
    short*  hn     = (short*)alloc((size_t)32768 * 512 * 2);                 // 32 MB (also: gated)
    short*  g      = (short*)alloc((size_t)32768 * 512 * 2);                 // 32 MB (also: head g2)
    short*  ut     = (short*)alloc((size_t)8 * 512 * 4096 * 2);              // 32 MB u^T / filtered
    float*  filt   = (float*)ut;   // overlay: filt (8 MB f32) dead before gemm_u writes ut
    float2* Fh     = (float2*)alloc((size_t)512 * 4096 * sizeof(float2));    // 16 MB

    twiddle_kernel<<<16, 256, 0, stream>>>(tw);
    transpose_cvt<<<dim3(48, 16, 8), 256, 0, stream>>>(win_w, winT8, 512, 1536);
    transpose_cvt<<<dim3(16, 16, 8), 256, 0, stream>>>(wout_w, woutT8, 512, 512);
    transpose_cvt<<<dim3(8, 16, 1), 256, 0, stream>>>(hw1, hw1T, 512, 256);
    embed_kernel<<<32768, 256, 0, stream>>>(x, eids, in_w, in_b, eemb, h);

    for (int d = 0; d < 8; ++d) {
        const short* winTd = winT8 + (size_t)d * 1536 * 512;
        mlp_kernel<<<dim3(64, 4), 256, 0, stream>>>(
            fw1 + d*64, fb1 + d*64, fw2 + (size_t)d*64*64, fb2 + d*64,
            fw3 + (size_t)d*64*512, fb3 + d*512, filt);
        fft_kernel<0><<<512, 256, 0, stream>>>(
            filt, nullptr, nullptr, nullptr, Fh, tw, nullptr, nullptr);
        ln_kernel<<<8192, 256, 0, stream>>>(h, ln_g + d*512, ln_b + d*512, hn);
        gemm_u<<<dim3(256, 4), 256, 0, stream>>>(
            hn, winTd + (size_t)512*512, win_b + d*1536 + 512, ut);
        gemm_vz<<<dim3(256, 4), 256, 0, stream>>>(
            hn, winTd, win_b + d*1536, g);
        fft_kernel<1><<<dim3(512, 4), 256, 0, stream>>>(
            nullptr, ut, Fh, ut, nullptr, tw, cw + (size_t)d*512*3, cb + d*512);
        gateT_kernel<<<dim3(64, 8, 8), 256, 0, stream>>>(ut, g, hn);
        gemm_bf16<1><<<dim3(256, 4), 256, 0, stream>>>(
            hn, woutT8 + (size_t)d*512*512, wout_b + d*512, nullptr, h, 512, 512);
    }

    ln_kernel<<<8192, 256, 0, stream>>>(h, fln_g, fln_b, hn);
    gemm_bf16<2><<<dim3(256, 2), 256, 0, stream>>>(
        hn, hw1T, hb1, (short*)g, nullptr, 256, 512);
    head_kernel<<<8192, 256, 0, stream>>>((short*)g, hw2, hb2, out);
}

// Round 10
// 2598.277 us; speedup vs baseline: 1.0777x; 1.0663x over previous
//
#include <hip/hip_runtime.h>
#include <hip/hip_bf16.h>

// ---------------------------------------------------------------------------
// HyenaPositioning forward: B=8, L=4096, IN=3, H=512, DEPTH=8, FH=64, OUT=2
// Per depth: LN -> gemm_u (u^T transposed out) + gemm_vz_split (v,z bf16)
//  -> fft<1> (conv3 fused into load, circular FFT conv, 2 batches packed)
//  -> gateT (v * filt * sigmoid(z), transpose back) -> gemm residual.
// proj (3H) never materialized. WS ~225 MB.
// ---------------------------------------------------------------------------

typedef short bf16x8 __attribute__((ext_vector_type(8)));
typedef float f32x4 __attribute__((ext_vector_type(4)));

__device__ __forceinline__ float bf2f(short s) {
    return __uint_as_float(((unsigned)(unsigned short)s) << 16);
}
__device__ __forceinline__ short f2bf(float f) {
    __hip_bfloat16 h = __float2bfloat16(f);
    return *reinterpret_cast<short*>(&h);
}
__device__ __forceinline__ float gelu_exact(float x) {
    return 0.5f * x * (1.0f + erff(x * 0.70710678118654752f));
}
__device__ __forceinline__ float sigmoidf_(float x) {
    return 1.0f / (1.0f + expf(-x));
}
__device__ __forceinline__ float2 cmul(float2 a, float2 b) {
    return make_float2(a.x*b.x - a.y*b.y, a.x*b.y + a.y*b.x);
}
__device__ __forceinline__ float2 cmulc(float2 a, float2 b) {  // a * conj(b)
    return make_float2(a.x*b.x + a.y*b.y, a.y*b.x - a.x*b.y);
}

__device__ __forceinline__ void gload_lds16(const void* gsrc, void* ldsdst) {
    __builtin_amdgcn_global_load_lds(
        (const __attribute__((address_space(1))) void*)gsrc,
        (__attribute__((address_space(3))) void*)ldsdst, 16, 0, 0);
}

// ---------------------------------------------------------------------------
// Embed: h = x@in_w + in_b + pe + edge_emb[edge_ids[b]]
// ---------------------------------------------------------------------------
__global__ __launch_bounds__(256)
void embed_kernel(const float* __restrict__ x, const int* __restrict__ eids,
                  const float* __restrict__ in_w, const float* __restrict__ in_b,
                  const float* __restrict__ eemb, float* __restrict__ h)
{
    const int bl = blockIdx.x;           // b*4096 + l
    const int b  = bl >> 12;
    const int l  = bl & 4095;
    const float x0 = x[bl*3 + 0], x1 = x[bl*3 + 1], x2 = x[bl*3 + 2];
    const int e = eids[b];
    #pragma unroll
    for (int i = 0; i < 2; ++i) {
        int col = threadIdx.x + 256*i;
        int k = col >> 1;
        float dv = expf(-0.03597789207803197f * (float)k);
        float ang = (float)l * dv;
        float pe = (col & 1) ? cosf(ang) : sinf(ang);
        float val = x0*in_w[col] + x1*in_w[512 + col] + x2*in_w[1024 + col]
                  + in_b[col] + pe + eemb[e*512 + col];
        h[(size_t)bl*512 + col] = val;
    }
}

// ---------------------------------------------------------------------------
// LayerNorm over H=512: one wave per row, output bf16
// ---------------------------------------------------------------------------
__global__ __launch_bounds__(256)
void ln_kernel(const float* __restrict__ hsrc, const float* __restrict__ g,
               const float* __restrict__ bta, short* __restrict__ out)
{
    const int m = blockIdx.x * 4 + (threadIdx.x >> 6);
    const int lane = threadIdx.x & 63;
    const float4* hp = (const float4*)(hsrc + (size_t)m * 512);
    float4 v0 = hp[lane*2], v1 = hp[lane*2 + 1];
    float xs[8] = {v0.x, v0.y, v0.z, v0.w, v1.x, v1.y, v1.z, v1.w};
    float s = 0.f, sq = 0.f;
    #pragma unroll
    for (int i = 0; i < 8; ++i) { s += xs[i]; sq += xs[i]*xs[i]; }
    #pragma unroll
    for (int o = 32; o > 0; o >>= 1) { s += __shfl_xor(s, o); sq += __shfl_xor(sq, o); }
    float mean = s * (1.f/512.f);
    float var  = sq * (1.f/512.f) - mean*mean;
    float rs = rsqrtf(var + 1e-5f);
    short res[8];
    #pragma unroll
    for (int i = 0; i < 8; ++i) {
        int col = lane*8 + i;
        res[i] = f2bf((xs[i] - mean) * rs * g[col] + bta[col]);
    }
    *(bf16x8*)(out + (size_t)m*512 + lane*8) = *(bf16x8*)res;
}

// ---------------------------------------------------------------------------
// gemm_bf16: generic A[M][K] x Bt[N][K]; EPI 1: f32 residual add (+bias),
// EPI 2: gelu->bf16. 128x128 tile, BK=64, 4 waves, global_load_lds + XOR-8
// swizzle, 16x16x32 bf16 MFMA.
// ---------------------------------------------------------------------------
template<int EPI>
__global__ __launch_bounds__(256)
void gemm_bf16(const short* __restrict__ A, const short* __restrict__ Bt,
               const float* __restrict__ bias, short* __restrict__ Cb,
               float* __restrict__ Cres, int N, int K)
{
    __shared__ __align__(16) short As[128 * 64];
    __shared__ __align__(16) short Bs[128 * 64];
    const int tid = threadIdx.x;
    const int w = tid >> 6, lane = tid & 63;
    const int m0 = blockIdx.x * 128, n0 = blockIdx.y * 128;
    const int wm = w >> 1, wn = w & 1;
    const int lane15 = lane & 15, lhi = lane >> 4;

    f32x4 acc[4][4];
    #pragma unroll
    for (int i = 0; i < 4; ++i)
        #pragma unroll
        for (int j = 0; j < 4; ++j) acc[i][j] = (f32x4){0.f, 0.f, 0.f, 0.f};

    for (int k0 = 0; k0 < K; k0 += 64) {
        #pragma unroll
        for (int i = 0; i < 4; ++i) {
            int row = 32*w + 8*i + (lane >> 3);
            int kch = (lane & 7) ^ (row & 7);
            gload_lds16(A + (size_t)(m0 + row) * K + k0 + kch*8, &As[(32*w + 8*i) * 64]);
        }
        #pragma unroll
        for (int i = 0; i < 4; ++i) {
            int row = 32*w + 8*i + (lane >> 3);
            int kch = (lane & 7) ^ (row & 7);
            gload_lds16(Bt + (size_t)(n0 + row) * K + k0 + kch*8, &Bs[(32*w + 8*i) * 64]);
        }
        __syncthreads();
        #pragma unroll
        for (int kk = 0; kk < 64; kk += 32) {
            bf16x8 af[4], bfr[4];
            const int kb = kk + lhi * 8;
            #pragma unroll
            for (int mi = 0; mi < 4; ++mi) {
                int row = wm*64 + mi*16 + lane15;
                af[mi] = *(const bf16x8*)&As[(row*64 + kb) ^ ((row & 7) << 3)];
            }
            #pragma unroll
            for (int ni = 0; ni < 4; ++ni) {
                int row = wn*64 + ni*16 + lane15;
                bfr[ni] = *(const bf16x8*)&Bs[(row*64 + kb) ^ ((row & 7) << 3)];
            }
            #pragma unroll
            for (int mi = 0; mi < 4; ++mi)
                #pragma unroll
                for (int ni = 0; ni < 4; ++ni)
                    acc[mi][ni] = __builtin_amdgcn_mfma_f32_16x16x32_bf16(
                        af[mi], bfr[ni], acc[mi][ni], 0, 0, 0);
        }
        __syncthreads();
    }
    #pragma unroll
    for (int mi = 0; mi < 4; ++mi) {
        #pragma unroll
        for (int ni = 0; ni < 4; ++ni) {
            int gcol = n0 + wn*64 + ni*16 + lane15;
            float bv = bias[gcol];
            #pragma unroll
            for (int r = 0; r < 4; ++r) {
                int grow = m0 + wm*64 + mi*16 + lhi*4 + r;
                float val = acc[mi][ni][r] + bv;
                if (EPI == 1) {
                    float* p = Cres + (size_t)grow * N + gcol;
                    *p += val;
                } else {
                    Cb[(size_t)grow * N + gcol] = f2bf(gelu_exact(val));
                }
            }
        }
    }
}

// ---------------------------------------------------------------------------
// gemm_vz_split: ONE dispatch, grid (256, 8). blockIdx.y<4 -> v-tiles
// (winT rows 0..511, bias 0..511); >=4 -> z-tiles (winT rows 1024..1535,
// bias 1024..1535). Same proven 84-VGPR / 32KB-LDS inner loop as gemm_bf16.
// Writes bf16 (+bias) to V or Z [32768][512].
// ---------------------------------------------------------------------------
__global__ __launch_bounds__(256)
void gemm_vz_split(const short* __restrict__ A, const short* __restrict__ BtW,
                   const float* __restrict__ biasW, short* __restrict__ V,
                   short* __restrict__ Z)
{
    __shared__ __align__(16) short As[128 * 64];
    __shared__ __align__(16) short Bs[128 * 64];
    const int tid = threadIdx.x;
    const int w = tid >> 6, lane = tid & 63;
    const int isz = blockIdx.y >> 2;
    const int m0 = blockIdx.x * 128, n0 = (blockIdx.y & 3) * 128;
    const short* Bt = BtW + (size_t)isz * 1024 * 512;
    const float* bias = biasW + isz * 1024;
    short* C = isz ? Z : V;
    const int wm = w >> 1, wn = w & 1;
    const int lane15 = lane & 15, lhi = lane >> 4;
    const int K = 512;

    f32x4 acc[4][4];
    #pragma unroll
    for (int i = 0; i < 4; ++i)
        #pragma unroll
        for (int j = 0; j < 4; ++j) acc[i][j] = (f32x4){0.f, 0.f, 0.f, 0.f};

    for (int k0 = 0; k0 < K; k0 += 64) {
        #pragma unroll
        for (int i = 0; i < 4; ++i) {
            int row = 32*w + 8*i + (lane >> 3);
            int kch = (lane & 7) ^ (row & 7);
            gload_lds16(A + (size_t)(m0 + row) * K + k0 + kch*8, &As[(32*w + 8*i) * 64]);
        }
        #pragma unroll
        for (int i = 0; i < 4; ++i) {
            int row = 32*w + 8*i + (lane >> 3);
            int kch = (lane & 7) ^ (row & 7);
            gload_lds16(Bt + (size_t)(n0 + row) * K + k0 + kch*8, &Bs[(32*w + 8*i) * 64]);
        }
        __syncthreads();
        #pragma unroll
        for (int kk = 0; kk < 64; kk += 32) {
            bf16x8 af[4], bfr[4];
            const int kb = kk + lhi * 8;
            #pragma unroll
            for (int mi = 0; mi < 4; ++mi) {
                int row = wm*64 + mi*16 + lane15;
                af[mi] = *(const bf16x8*)&As[(row*64 + kb) ^ ((row & 7) << 3)];
            }
            #pragma unroll
            for (int ni = 0; ni < 4; ++ni) {
                int row = wn*64 + ni*16 + lane15;
                bfr[ni] = *(const bf16x8*)&Bs[(row*64 + kb) ^ ((row & 7) << 3)];
            }
            #pragma unroll
            for (int mi = 0; mi < 4; ++mi)
                #pragma unroll
                for (int ni = 0; ni < 4; ++ni)
                    acc[mi][ni] = __builtin_amdgcn_mfma_f32_16x16x32_bf16(
                        af[mi], bfr[ni], acc[mi][ni], 0, 0, 0);
        }
        __syncthreads();
    }
    #pragma unroll
    for (int mi = 0; mi < 4; ++mi) {
        #pragma unroll
        for (int ni = 0; ni < 4; ++ni) {
            int gcol = n0 + wn*64 + ni*16 + lane15;
            float bv = bias[gcol];
            #pragma unroll
            for (int r = 0; r < 4; ++r) {
                int grow = m0 + wm*64 + mi*16 + lhi*4 + r;
                C[(size_t)grow * 512 + gcol] = f2bf(acc[mi][ni][r] + bv);
            }
        }
    }
}

// ---------------------------------------------------------------------------
// gemm_u: A=hn[32768][512] x Bt=winT u-rows [512][512] -> u^T (B,H,L) bf16.
// Epilogue transposes the 128x128 tile in LDS (reusing As/Bs) with an XOR
// swizzle on l, then stores 256B row segments of u^T.
// ---------------------------------------------------------------------------
__global__ __launch_bounds__(256)
void gemm_u(const short* __restrict__ A, const short* __restrict__ Bt,
            const float* __restrict__ bias, short* __restrict__ ut)
{
    __shared__ __align__(16) short smem[128 * 128];   // As | Bs, then T
    short* As = smem;
    short* Bs = smem + 128*64;
    const int tid = threadIdx.x;
    const int w = tid >> 6, lane = tid & 63;
    const int m0 = blockIdx.x * 128, n0 = blockIdx.y * 128;
    const int wm = w >> 1, wn = w & 1;
    const int lane15 = lane & 15, lhi = lane >> 4;
    const int K = 512;

    f32x4 acc[4][4];
    #pragma unroll
    for (int i = 0; i < 4; ++i)
        #pragma unroll
        for (int j = 0; j < 4; ++j) acc[i][j] = (f32x4){0.f, 0.f, 0.f, 0.f};

    for (int k0 = 0; k0 < K; k0 += 64) {
        #pragma unroll
        for (int i = 0; i < 4; ++i) {
            int row = 32*w + 8*i + (lane >> 3);
            int kch = (lane & 7) ^ (row & 7);
            gload_lds16(A + (size_t)(m0 + row) * K + k0 + kch*8, &As[(32*w + 8*i) * 64]);
        }
        #pragma unroll
        for (int i = 0; i < 4; ++i) {
            int row = 32*w + 8*i + (lane >> 3);
            int kch = (lane & 7) ^ (row & 7);
            gload_lds16(Bt + (size_t)(n0 + row) * K + k0 + kch*8, &Bs[(32*w + 8*i) * 64]);
        }
        __syncthreads();
        #pragma unroll
        for (int kk = 0; kk < 64; kk += 32) {
            bf16x8 af[4], bfr[4];
            const int kb = kk + lhi * 8;
            #pragma unroll
            for (int mi = 0; mi < 4; ++mi) {
                int row = wm*64 + mi*16 + lane15;
                af[mi] = *(const bf16x8*)&As[(row*64 + kb) ^ ((row & 7) << 3)];
            }
            #pragma unroll
            for (int ni = 0; ni < 4; ++ni) {
                int row = wn*64 + ni*16 + lane15;
                bfr[ni] = *(const bf16x8*)&Bs[(row*64 + kb) ^ ((row & 7) << 3)];
            }
            #pragma unroll
            for (int mi = 0; mi < 4; ++mi)
                #pragma unroll
                for (int ni = 0; ni < 4; ++ni)
                    acc[mi][ni] = __builtin_amdgcn_mfma_f32_16x16x32_bf16(
                        af[mi], bfr[ni], acc[mi][ni], 0, 0, 0);
        }
        __syncthreads();
    }
    // T[h][l]: index = h*128 + (l ^ ((h&7)<<3))
    #pragma unroll
    for (int mi = 0; mi < 4; ++mi) {
        #pragma unroll
        for (int ni = 0; ni < 4; ++ni) {
            int hcol = wn*64 + ni*16 + lane15;
            float bv = bias[n0 + hcol];
            #pragma unroll
            for (int r = 0; r < 4; ++r) {
                int bl = wm*64 + mi*16 + lhi*4 + r;
                smem[hcol*128 + (bl ^ ((hcol & 7) << 3))] = f2bf(acc[mi][ni][r] + bv);
            }
        }
    }
    __syncthreads();
    const int b = m0 >> 12, l0 = m0 & 4095;
    #pragma unroll
    for (int p = 0; p < 8; ++p) {
        int hh = p*16 + (tid >> 4);
        int lbase = (tid & 15) * 8;
        bf16x8 v = *(const bf16x8*)&smem[hh*128 + (lbase ^ ((hh & 7) << 3))];
        *(bf16x8*)(ut + ((size_t)(b*512 + n0 + hh))*4096 + l0 + lbase) = v;
    }
}

// ---------------------------------------------------------------------------
// Filter MLP: writes filt_t[h][l] f32 (512 x 4096)
// ---------------------------------------------------------------------------
__global__ __launch_bounds__(256)
void mlp_kernel(const float* __restrict__ fw1, const float* __restrict__ fb1,
                const float* __restrict__ fw2, const float* __restrict__ fb2,
                const float* __restrict__ fw3, const float* __restrict__ fb3,
                float* __restrict__ filt_t)
{
    __shared__ float F1[64][65];
    __shared__ float F2[64][65];
    __shared__ float FO[64][129];
    const int lt = blockIdx.x, ns = blockIdx.y;
    const int l0 = lt * 64, nb = ns * 128;
    const int tid = threadIdx.x;
    for (int i = tid; i < 4096; i += 256) {
        int l = i >> 6, j = i & 63;
        float tv = (float)(l0 + l) * (1.0f / 4095.0f);
        F1[l][j] = gelu_exact(tv * fw1[j] + fb1[j]);
    }
    __syncthreads();
    {
        int j = tid & 63, lb = tid >> 6;
        for (int li = 0; li < 16; ++li) {
            int l = lb*16 + li;
            float sum = fb2[j];
            #pragma unroll
            for (int k = 0; k < 64; ++k) sum += F1[l][k] * fw2[k*64 + j];
            F2[l][j] = gelu_exact(sum);
        }
    }
    __syncthreads();
    {
        const int nn = tid & 127;
        const int lofs = tid >> 7;
        for (int jj = 0; jj < 32; ++jj) {
            int l = lofs + 2*jj;
            float sum = fb3[nb + nn];
            #pragma unroll
            for (int k = 0; k < 64; ++k) sum += F2[l][k] * fw3[k*512 + nb + nn];
            FO[l][nn] = sum;
        }
    }
    __syncthreads();
    for (int i = tid; i < 8192; i += 256) {
        int nn = i >> 6, l = i & 63;
        filt_t[(size_t)(nb + nn) * 4096 + l0 + l] = FO[l][nn];
    }
}

// ---------------------------------------------------------------------------
// Radix-4 FFT (4096 pts), in-LDS, padded indexing.
// MODE 0: real f32 filt row -> spectrum (digit-reversed) to Fout.
// MODE 1: load u^T bf16 (2 batches packed re/im), depthwise conv3 in LDS,
//         fwd FFT, multiply by Fh (fused in inverse stage 0), inverse,
//         write filtered bf16 (in place over u^T).
// ---------------------------------------------------------------------------
#define FIDX(i) ((i) + ((i) >> 4))

template<int MODE>
__global__ __launch_bounds__(256)
void fft_kernel(const float* __restrict__ rin_f, const short* __restrict__ rin_h,
                const float2* __restrict__ Fh, short* __restrict__ rout_h,
                float2* __restrict__ Fout, const float2* __restrict__ tw,
                const float* __restrict__ cw3, const float* __restrict__ cbv)
{
    __shared__ float2 S[4096 + 256];
    const int tid = threadIdx.x;
    const int hh = blockIdx.x;
    if (MODE == 0) {
        const float* src = rin_f + (size_t)hh * 4096;
        for (int i = tid; i < 4096; i += 256) S[FIDX(i)] = make_float2(src[i], 0.f);
        __syncthreads();
    } else {
        const int b0 = blockIdx.y * 2, b1 = b0 + 1;
        const short* s0 = rin_h + ((size_t)b0 * 512 + hh) * 4096;
        const short* s1 = rin_h + ((size_t)b1 * 512 + hh) * 4096;
        for (int i = tid; i < 4096; i += 256)
            S[FIDX(i)] = make_float2(bf2f(s0[i]), bf2f(s1[i]));
        __syncthreads();
        // depthwise conv3, pad=1 (applies to both packed batches)
        const float c0 = cw3[hh*3 + 0], c1 = cw3[hh*3 + 1], c2 = cw3[hh*3 + 2];
        const float cb = cbv[hh];
        float2 r[16];
        #pragma unroll
        for (int k = 0; k < 16; ++k) {
            int i = tid + 256*k;
            float2 um = (i == 0)    ? make_float2(0.f, 0.f) : S[FIDX(i-1)];
            float2 uc = S[FIDX(i)];
            float2 up = (i == 4095) ? make_float2(0.f, 0.f) : S[FIDX(i+1)];
            r[k] = make_float2(um.x*c0 + uc.x*c1 + up.x*c2 + cb,
                               um.y*c0 + uc.y*c1 + up.y*c2 + cb);
        }
        __syncthreads();
        #pragma unroll
        for (int k = 0; k < 16; ++k) S[FIDX(tid + 256*k)] = r[k];
        __syncthreads();
    }
    // forward DIF radix-4: natural in -> digit-reversed out
    #pragma unroll
    for (int s = 0; s < 6; ++s) {
        const int lq = 10 - 2*s;
        const int q = 1 << lq;
        const int tf = 1 << (2*s);
        for (int bfy = tid; bfy < 1024; bfy += 256) {
            const int j = bfy & (q - 1);
            const int base = ((bfy >> lq) << (lq + 2)) + j;
            float2 a = S[FIDX(base)];
            float2 b = S[FIDX(base + q)];
            float2 c = S[FIDX(base + 2*q)];
            float2 d = S[FIDX(base + 3*q)];
            float2 t0 = make_float2(a.x + c.x, a.y + c.y);
            float2 t1 = make_float2(a.x - c.x, a.y - c.y);
            float2 t2 = make_float2(b.x + d.x, b.y + d.y);
            float2 t3 = make_float2(b.x - d.x, b.y - d.y);
            float2 o0 = make_float2(t0.x + t2.x, t0.y + t2.y);
            float2 p1 = make_float2(t1.x + t3.y, t1.y - t3.x);   // t1 - i*t3
            float2 p2 = make_float2(t0.x - t2.x, t0.y - t2.y);
            float2 p3 = make_float2(t1.x - t3.y, t1.y + t3.x);   // t1 + i*t3
            S[FIDX(base)]       = o0;
            S[FIDX(base + q)]   = cmul(p1, tw[j * tf]);
            S[FIDX(base + 2*q)] = cmul(p2, tw[2 * j * tf]);
            S[FIDX(base + 3*q)] = cmul(p3, tw[3 * j * tf]);
        }
        __syncthreads();
    }
    if (MODE == 0) {
        float2* dst = Fout + (size_t)hh * 4096;
        for (int i = tid; i < 4096; i += 256) dst[i] = S[FIDX(i)];
        return;
    }
    // inverse stages (exact algebraic inverse), spectrum multiply fused at s=0
    const float2* F = Fh + (size_t)hh * 4096;
    #pragma unroll
    for (int s = 0; s < 6; ++s) {
        const int q = 1 << (2*s);
        const int tf = 1 << (10 - 2*s);
        for (int bfy = tid; bfy < 1024; bfy += 256) {
            const int j = bfy & (q - 1);
            const int base = ((bfy >> (2*s)) << (2*s + 2)) + j;
            float2 u0 = S[FIDX(base)];
            float2 u1 = S[FIDX(base + q)];
            float2 u2 = S[FIDX(base + 2*q)];
            float2 u3 = S[FIDX(base + 3*q)];
            if (s == 0) {
                u0 = cmul(u0, F[base]);     u1 = cmul(u1, F[base + 1]);
                u2 = cmul(u2, F[base + 2]); u3 = cmul(u3, F[base + 3]);
            } else {
                u1 = cmulc(u1, tw[j * tf]);
                u2 = cmulc(u2, tw[2 * j * tf]);
                u3 = cmulc(u3, tw[3 * j * tf]);
            }
            float2 pp = make_float2(u0.x + u2.x, u0.y + u2.y);
            float2 mm = make_float2(u0.x - u2.x, u0.y - u2.y);
            float2 rr = make_float2(u1.x + u3.x, u1.y + u3.y);
            float2 tt = make_float2(u1.x - u3.x, u1.y - u3.y);
            S[FIDX(base)]       = make_float2(pp.x + rr.x, pp.y + rr.y);
            S[FIDX(base + q)]   = make_float2(mm.x - tt.y, mm.y + tt.x);
            S[FIDX(base + 2*q)] = make_float2(pp.x - rr.x, pp.y - rr.y);
            S[FIDX(base + 3*q)] = make_float2(mm.x + tt.y, mm.y - tt.x);
        }
        __syncthreads();
    }
    const int b0 = blockIdx.y * 2, b1 = b0 + 1;
    short* d0 = rout_h + ((size_t)b0 * 512 + hh) * 4096;
    short* d1 = rout_h + ((size_t)b1 * 512 + hh) * 4096;
    const float inv = 1.0f / 4096.0f;
    for (int i = tid; i < 4096; i += 256) {
        float2 v = S[FIDX(i)];
        d0[i] = f2bf(v.x * inv);
        d1[i] = f2bf(v.y * inv);
    }
}

// ---------------------------------------------------------------------------
// Gate: gated = v * filtered * sigmoid(z); transpose ft (B,H,L)->(B,L,H)
// ---------------------------------------------------------------------------
__global__ __launch_bounds__(256)
void gateT_kernel(const short* __restrict__ ft, const short* __restrict__ v,
                  const short* __restrict__ z, short* __restrict__ gated)
{
    __shared__ float Fd[64][65];
    const int lt = blockIdx.x, ht = blockIdx.y, b = blockIdx.z;
    const int l0 = lt * 64, h0 = ht * 64;
    const int tid = threadIdx.x, c63 = tid & 63, r4 = tid >> 6;
    for (int j = 0; j < 16; ++j) {
        int hh = r4 + 4*j;
        Fd[hh][c63] = bf2f(ft[((size_t)(b*512 + h0 + hh)) * 4096 + l0 + c63]);
    }
    __syncthreads();
    for (int j = 0; j < 16; ++j) {
        int l = l0 + r4 + 4*j;
        size_t row = (size_t)(b*4096 + l) * 512;
        float vv = bf2f(v[row + h0 + c63]);
        float zz = bf2f(z[row + h0 + c63]);
        float f = Fd[c63][r4 + 4*j];
        gated[row + h0 + c63] = f2bf(vv * f * sigmoidf_(zz));
    }
}

// ---------------------------------------------------------------------------
// Weight transpose + f32->bf16: in [R][C] -> out [C][R], z = depth slice
// ---------------------------------------------------------------------------
__global__ __launch_bounds__(256)
void transpose_cvt(const float* __restrict__ in, short* __restrict__ out, int R, int C)
{
    __shared__ float T[32][33];
    const size_t off = (size_t)blockIdx.z * R * C;
    const float* ip = in + off;
    short* op = out + off;
    int tx = threadIdx.x & 31, ty = threadIdx.x >> 5;
    int r0 = blockIdx.y * 32, c0 = blockIdx.x * 32;
    for (int j = 0; j < 4; ++j)
        T[ty + 8*j][tx] = ip[(size_t)(r0 + ty + 8*j) * C + c0 + tx];
    __syncthreads();
    for (int j = 0; j < 4; ++j)
        op[(size_t)(c0 + ty + 8*j) * R + r0 + tx] = f2bf(T[tx][ty + 8*j]);
}

__global__ void twiddle_kernel(float2* tw)
{
    int k = blockIdx.x * 256 + threadIdx.x;
    if (k < 4096) {
        float ang = -(float)(6.283185307179586 / 4096.0) * (float)k;
        tw[k] = make_float2(cosf(ang), sinf(ang));
    }
}

// ---------------------------------------------------------------------------
// Head: out[m][0..1] = g2[m]@hw2 + hb2 (one wave per row)
// ---------------------------------------------------------------------------
__global__ __launch_bounds__(256)
void head_kernel(const short* __restrict__ g2, const float* __restrict__ hw2,
                 const float* __restrict__ hb2, float* __restrict__ out)
{
    const int m = blockIdx.x * 4 + (threadIdx.x >> 6);
    const int lane = threadIdx.x & 63;
    const short* row = g2 + (size_t)m * 256;
    float a0 = 0.f, a1 = 0.f;
    #pragma unroll
    for (int i = 0; i < 4; ++i) {
        int k = lane*4 + i;
        float gv = bf2f(row[k]);
        a0 += gv * hw2[2*k];
        a1 += gv * hw2[2*k + 1];
    }
    #pragma unroll
    for (int o = 32; o > 0; o >>= 1) { a0 += __shfl_xor(a0, o); a1 += __shfl_xor(a1, o); }
    if (lane == 0) {
        out[(size_t)m*2]     = a0 + hb2[0];
        out[(size_t)m*2 + 1] = a1 + hb2[1];
    }
}

// ---------------------------------------------------------------------------
extern "C" void kernel_launch(void* const* d_in, const int* in_sizes, int n_in,
                              void* d_out, int out_size, void* d_ws, size_t ws_size,
                              hipStream_t stream)
{
    const float* x      = (const float*)d_in[0];
    const int*   eids   = (const int*)d_in[1];
    const float* in_w   = (const float*)d_in[2];
    const float* in_b   = (const float*)d_in[3];
    const float* eemb   = (const float*)d_in[4];
    const float* ln_g   = (const float*)d_in[5];
    const float* ln_b   = (const float*)d_in[6];
    const float* fw1    = (const float*)d_in[7];
    const float* fb1    = (const float*)d_in[8];
    const float* fw2    = (const float*)d_in[9];
    const float* fb2    = (const float*)d_in[10];
    const float* fw3    = (const float*)d_in[11];
    const float* fb3    = (const float*)d_in[12];
    const float* cw     = (const float*)d_in[13];
    const float* cb     = (const float*)d_in[14];
    const float* win_w  = (const float*)d_in[15];
    const float* win_b  = (const float*)d_in[16];
    const float* wout_w = (const float*)d_in[17];
    const float* wout_b = (const float*)d_in[18];
    const float* fln_g  = (const float*)d_in[19];
    const float* fln_b  = (const float*)d_in[20];
    const float* hw1    = (const float*)d_in[21];
    const float* hb1    = (const float*)d_in[22];
    const float* hw2    = (const float*)d_in[23];
    const float* hb2    = (const float*)d_in[24];
    float* out = (float*)d_out;

    // ---- workspace layout (~225 MB) ----
    char* p = (char*)d_ws;
    auto alloc = [&](size_t bytes) { char* r = p; p += (bytes + 255) & ~(size_t)255; return r; };
    float2* tw     = (float2*)alloc((size_t)4096 * sizeof(float2));          // 32 KB
    short*  winT8  = (short*)alloc((size_t)8 * 1536 * 512 * 2);              // 12.6 MB
    short*  woutT8 = (short*)alloc((size_t)8 * 512 * 512 * 2);               // 4.2 MB
    short*  hw1T   = (short*)alloc((size_t)256 * 512 * 2);                   // 0.26 MB
    float*  h      = (float*)alloc((size_t)32768 * 512 * 4);                 // 64 MB
    short*  hn     = (short*)alloc((size_t)32768 * 512 * 2);                 // 32 MB (also: gated)
    short*  v      = (short*)alloc((size_t)32768 * 512 * 2);                 // 32 MB (also: head g2)
    short*  z      = (short*)alloc((size_t)32768 * 512 * 2);                 // 32 MB
    short*  ut     = (short*)alloc((size_t)8 * 512 * 4096 * 2);              // 32 MB u^T / filtered
    float*  filt   = (float*)ut;   // overlay: filt (8 MB f32) dead before gemm_u writes ut
    float2* Fh     = (float2*)alloc((size_t)512 * 4096 * sizeof(float2));    // 16 MB

    twiddle_kernel<<<16, 256, 0, stream>>>(tw);
    transpose_cvt<<<dim3(48, 16, 8), 256, 0, stream>>>(win_w, winT8, 512, 1536);
    transpose_cvt<<<dim3(16, 16, 8), 256, 0, stream>>>(wout_w, woutT8, 512, 512);
    transpose_cvt<<<dim3(8, 16, 1), 256, 0, stream>>>(hw1, hw1T, 512, 256);
    embed_kernel<<<32768, 256, 0, stream>>>(x, eids, in_w, in_b, eemb, h);

    for (int d = 0; d < 8; ++d) {
        const short* winTd = winT8 + (size_t)d * 1536 * 512;
        mlp_kernel<<<dim3(64, 4), 256, 0, stream>>>(
            fw1 + d*64, fb1 + d*64, fw2 + (size_t)d*64*64, fb2 + d*64,
            fw3 + (size_t)d*64*512, fb3 + d*512, filt);
        fft_kernel<0><<<512, 256, 0, stream>>>(
            filt, nullptr, nullptr, nullptr, Fh, tw, nullptr, nullptr);
        ln_kernel<<<8192, 256, 0, stream>>>(h, ln_g + d*512, ln_b + d*512, hn);
        gemm_u<<<dim3(256, 4), 256, 0, stream>>>(
            hn, winTd + (size_t)512*512, win_b + d*1536 + 512, ut);
        gemm_vz_split<<<dim3(256, 8), 256, 0, stream>>>(
            hn, winTd, win_b + d*1536, v, z);
        fft_kernel<1><<<dim3(512, 4), 256, 0, stream>>>(
            nullptr, ut, Fh, ut, nullptr, tw, cw + (size_t)d*512*3, cb + d*512);
        gateT_kernel<<<dim3(64, 8, 8), 256, 0, stream>>>(ut, v, z, hn);
        gemm_bf16<1><<<dim3(256, 4), 256, 0, stream>>>(
            hn, woutT8 + (size_t)d*512*512, wout_b + d*512, nullptr, h, 512, 512);
    }

    ln_kernel<<<8192, 256, 0, stream>>>(h, fln_g, fln_b, hn);
    gemm_bf16<2><<<dim3(256, 2), 256, 0, stream>>>(
        hn, hw1T, hb1, (short*)v, nullptr, 256, 512);
    head_kernel<<<8192, 256, 0, stream>>>((short*)v, hw2, hb2, out);
}

// Round 11
// 2401.366 us; speedup vs baseline: 1.1661x; 1.0820x over previous
//
#include <hip/hip_runtime.h>
#include <hip/hip_bf16.h>

// ---------------------------------------------------------------------------
// HyenaPositioning forward: B=8, L=4096, IN=3, H=512, DEPTH=8, FH=64, OUT=2
// Per depth: LN(+residual-add of prev delta) -> gemm_u (u^T) + gemm_vz_split
//  -> fft<1> (conv3 fused, circular FFT conv, 2 batches packed) -> gateT
//  -> gemm_bf16<0> writes bf16 delta (residual folded into next LN).
// proj (3H) never materialized. WS ~225 MB.
// ---------------------------------------------------------------------------

typedef short bf16x8 __attribute__((ext_vector_type(8)));
typedef float f32x4 __attribute__((ext_vector_type(4)));

__device__ __forceinline__ float bf2f(short s) {
    return __uint_as_float(((unsigned)(unsigned short)s) << 16);
}
__device__ __forceinline__ short f2bf(float f) {
    __hip_bfloat16 h = __float2bfloat16(f);
    return *reinterpret_cast<short*>(&h);
}
__device__ __forceinline__ float gelu_exact(float x) {
    return 0.5f * x * (1.0f + erff(x * 0.70710678118654752f));
}
__device__ __forceinline__ float sigmoidf_(float x) {
    return 1.0f / (1.0f + expf(-x));
}
__device__ __forceinline__ float2 cmul(float2 a, float2 b) {
    return make_float2(a.x*b.x - a.y*b.y, a.x*b.y + a.y*b.x);
}
__device__ __forceinline__ float2 cmulc(float2 a, float2 b) {  // a * conj(b)
    return make_float2(a.x*b.x + a.y*b.y, a.y*b.x - a.x*b.y);
}

__device__ __forceinline__ void gload_lds16(const void* gsrc, void* ldsdst) {
    __builtin_amdgcn_global_load_lds(
        (const __attribute__((address_space(1))) void*)gsrc,
        (__attribute__((address_space(3))) void*)ldsdst, 16, 0, 0);
}

// ---------------------------------------------------------------------------
// Embed: h = x@in_w + in_b + pe + edge_emb[edge_ids[b]]
// ---------------------------------------------------------------------------
__global__ __launch_bounds__(256)
void embed_kernel(const float* __restrict__ x, const int* __restrict__ eids,
                  const float* __restrict__ in_w, const float* __restrict__ in_b,
                  const float* __restrict__ eemb, float* __restrict__ h)
{
    const int bl = blockIdx.x;           // b*4096 + l
    const int b  = bl >> 12;
    const int l  = bl & 4095;
    const float x0 = x[bl*3 + 0], x1 = x[bl*3 + 1], x2 = x[bl*3 + 2];
    const int e = eids[b];
    #pragma unroll
    for (int i = 0; i < 2; ++i) {
        int col = threadIdx.x + 256*i;
        int k = col >> 1;
        float dv = expf(-0.03597789207803197f * (float)k);
        float ang = (float)l * dv;
        float pe = (col & 1) ? cosf(ang) : sinf(ang);
        float val = x0*in_w[col] + x1*in_w[512 + col] + x2*in_w[1024 + col]
                  + in_b[col] + pe + eemb[e*512 + col];
        h[(size_t)bl*512 + col] = val;
    }
}

// ---------------------------------------------------------------------------
// LayerNorm over H=512 with fused residual add: if delta!=null,
// h_new = h + bf16(delta) is written back to h, and LN(h_new) -> out (bf16).
// One wave per row.
// ---------------------------------------------------------------------------
__global__ __launch_bounds__(256)
void ln_kernel(float* __restrict__ hsrc, const short* __restrict__ delta,
               const float* __restrict__ g, const float* __restrict__ bta,
               short* __restrict__ out)
{
    const int m = blockIdx.x * 4 + (threadIdx.x >> 6);
    const int lane = threadIdx.x & 63;
    float4* hp = (float4*)(hsrc + (size_t)m * 512);
    float4 v0 = hp[lane*2], v1 = hp[lane*2 + 1];
    float xs[8] = {v0.x, v0.y, v0.z, v0.w, v1.x, v1.y, v1.z, v1.w};
    if (delta) {
        bf16x8 dv = *(const bf16x8*)(delta + (size_t)m*512 + lane*8);
        #pragma unroll
        for (int i = 0; i < 8; ++i) xs[i] += bf2f(dv[i]);
        float4 w0 = make_float4(xs[0], xs[1], xs[2], xs[3]);
        float4 w1 = make_float4(xs[4], xs[5], xs[6], xs[7]);
        hp[lane*2] = w0; hp[lane*2 + 1] = w1;
    }
    float s = 0.f, sq = 0.f;
    #pragma unroll
    for (int i = 0; i < 8; ++i) { s += xs[i]; sq += xs[i]*xs[i]; }
    #pragma unroll
    for (int o = 32; o > 0; o >>= 1) { s += __shfl_xor(s, o); sq += __shfl_xor(sq, o); }
    float mean = s * (1.f/512.f);
    float var  = sq * (1.f/512.f) - mean*mean;
    float rs = rsqrtf(var + 1e-5f);
    short res[8];
    #pragma unroll
    for (int i = 0; i < 8; ++i) {
        int col = lane*8 + i;
        res[i] = f2bf((xs[i] - mean) * rs * g[col] + bta[col]);
    }
    *(bf16x8*)(out + (size_t)m*512 + lane*8) = *(bf16x8*)res;
}

// ---------------------------------------------------------------------------
// gemm_bf16: generic A[M][K] x Bt[N][K]; EPI 0: bf16 store (+bias),
// EPI 2: gelu->bf16. 128x128 tile, BK=64, 4 waves, global_load_lds + XOR-8
// swizzle, 16x16x32 bf16 MFMA.
// ---------------------------------------------------------------------------
template<int EPI>
__global__ __launch_bounds__(256)
void gemm_bf16(const short* __restrict__ A, const short* __restrict__ Bt,
               const float* __restrict__ bias, short* __restrict__ Cb,
               int N, int K)
{
    __shared__ __align__(16) short As[128 * 64];
    __shared__ __align__(16) short Bs[128 * 64];
    const int tid = threadIdx.x;
    const int w = tid >> 6, lane = tid & 63;
    const int m0 = blockIdx.x * 128, n0 = blockIdx.y * 128;
    const int wm = w >> 1, wn = w & 1;
    const int lane15 = lane & 15, lhi = lane >> 4;

    f32x4 acc[4][4];
    #pragma unroll
    for (int i = 0; i < 4; ++i)
        #pragma unroll
        for (int j = 0; j < 4; ++j) acc[i][j] = (f32x4){0.f, 0.f, 0.f, 0.f};

    for (int k0 = 0; k0 < K; k0 += 64) {
        #pragma unroll
        for (int i = 0; i < 4; ++i) {
            int row = 32*w + 8*i + (lane >> 3);
            int kch = (lane & 7) ^ (row & 7);
            gload_lds16(A + (size_t)(m0 + row) * K + k0 + kch*8, &As[(32*w + 8*i) * 64]);
        }
        #pragma unroll
        for (int i = 0; i < 4; ++i) {
            int row = 32*w + 8*i + (lane >> 3);
            int kch = (lane & 7) ^ (row & 7);
            gload_lds16(Bt + (size_t)(n0 + row) * K + k0 + kch*8, &Bs[(32*w + 8*i) * 64]);
        }
        __syncthreads();
        #pragma unroll
        for (int kk = 0; kk < 64; kk += 32) {
            bf16x8 af[4], bfr[4];
            const int kb = kk + lhi * 8;
            #pragma unroll
            for (int mi = 0; mi < 4; ++mi) {
                int row = wm*64 + mi*16 + lane15;
                af[mi] = *(const bf16x8*)&As[(row*64 + kb) ^ ((row & 7) << 3)];
            }
            #pragma unroll
            for (int ni = 0; ni < 4; ++ni) {
                int row = wn*64 + ni*16 + lane15;
                bfr[ni] = *(const bf16x8*)&Bs[(row*64 + kb) ^ ((row & 7) << 3)];
            }
            #pragma unroll
            for (int mi = 0; mi < 4; ++mi)
                #pragma unroll
                for (int ni = 0; ni < 4; ++ni)
                    acc[mi][ni] = __builtin_amdgcn_mfma_f32_16x16x32_bf16(
                        af[mi], bfr[ni], acc[mi][ni], 0, 0, 0);
        }
        __syncthreads();
    }
    #pragma unroll
    for (int mi = 0; mi < 4; ++mi) {
        #pragma unroll
        for (int ni = 0; ni < 4; ++ni) {
            int gcol = n0 + wn*64 + ni*16 + lane15;
            float bv = bias[gcol];
            #pragma unroll
            for (int r = 0; r < 4; ++r) {
                int grow = m0 + wm*64 + mi*16 + lhi*4 + r;
                float val = acc[mi][ni][r] + bv;
                if (EPI == 0) {
                    Cb[(size_t)grow * N + gcol] = f2bf(val);
                } else {
                    Cb[(size_t)grow * N + gcol] = f2bf(gelu_exact(val));
                }
            }
        }
    }
}

// ---------------------------------------------------------------------------
// gemm_vz_split: ONE dispatch, grid (256, 8). blockIdx.y<4 -> v-tiles
// (winT rows 0..511, bias 0..511); >=4 -> z-tiles (winT rows 1024..1535,
// bias 1024..1535). Same proven 84-VGPR / 32KB-LDS inner loop as gemm_bf16.
// Writes bf16 (+bias) to V or Z [32768][512].
// ---------------------------------------------------------------------------
__global__ __launch_bounds__(256)
void gemm_vz_split(const short* __restrict__ A, const short* __restrict__ BtW,
                   const float* __restrict__ biasW, short* __restrict__ V,
                   short* __restrict__ Z)
{
    __shared__ __align__(16) short As[128 * 64];
    __shared__ __align__(16) short Bs[128 * 64];
    const int tid = threadIdx.x;
    const int w = tid >> 6, lane = tid & 63;
    const int isz = blockIdx.y >> 2;
    const int m0 = blockIdx.x * 128, n0 = (blockIdx.y & 3) * 128;
    const short* Bt = BtW + (size_t)isz * 1024 * 512;
    const float* bias = biasW + isz * 1024;
    short* C = isz ? Z : V;
    const int wm = w >> 1, wn = w & 1;
    const int lane15 = lane & 15, lhi = lane >> 4;
    const int K = 512;

    f32x4 acc[4][4];
    #pragma unroll
    for (int i = 0; i < 4; ++i)
        #pragma unroll
        for (int j = 0; j < 4; ++j) acc[i][j] = (f32x4){0.f, 0.f, 0.f, 0.f};

    for (int k0 = 0; k0 < K; k0 += 64) {
        #pragma unroll
        for (int i = 0; i < 4; ++i) {
            int row = 32*w + 8*i + (lane >> 3);
            int kch = (lane & 7) ^ (row & 7);
            gload_lds16(A + (size_t)(m0 + row) * K + k0 + kch*8, &As[(32*w + 8*i) * 64]);
        }
        #pragma unroll
        for (int i = 0; i < 4; ++i) {
            int row = 32*w + 8*i + (lane >> 3);
            int kch = (lane & 7) ^ (row & 7);
            gload_lds16(Bt + (size_t)(n0 + row) * K + k0 + kch*8, &Bs[(32*w + 8*i) * 64]);
        }
        __syncthreads();
        #pragma unroll
        for (int kk = 0; kk < 64; kk += 32) {
            bf16x8 af[4], bfr[4];
            const int kb = kk + lhi * 8;
            #pragma unroll
            for (int mi = 0; mi < 4; ++mi) {
                int row = wm*64 + mi*16 + lane15;
                af[mi] = *(const bf16x8*)&As[(row*64 + kb) ^ ((row & 7) << 3)];
            }
            #pragma unroll
            for (int ni = 0; ni < 4; ++ni) {
                int row = wn*64 + ni*16 + lane15;
                bfr[ni] = *(const bf16x8*)&Bs[(row*64 + kb) ^ ((row & 7) << 3)];
            }
            #pragma unroll
            for (int mi = 0; mi < 4; ++mi)
                #pragma unroll
                for (int ni = 0; ni < 4; ++ni)
                    acc[mi][ni] = __builtin_amdgcn_mfma_f32_16x16x32_bf16(
                        af[mi], bfr[ni], acc[mi][ni], 0, 0, 0);
        }
        __syncthreads();
    }
    #pragma unroll
    for (int mi = 0; mi < 4; ++mi) {
        #pragma unroll
        for (int ni = 0; ni < 4; ++ni) {
            int gcol = n0 + wn*64 + ni*16 + lane15;
            float bv = bias[gcol];
            #pragma unroll
            for (int r = 0; r < 4; ++r) {
                int grow = m0 + wm*64 + mi*16 + lhi*4 + r;
                C[(size_t)grow * 512 + gcol] = f2bf(acc[mi][ni][r] + bv);
            }
        }
    }
}

// ---------------------------------------------------------------------------
// gemm_u: A=hn[32768][512] x Bt=winT u-rows [512][512] -> u^T (B,H,L) bf16.
// Epilogue transposes the 128x128 tile in LDS (reusing As/Bs) with an XOR
// swizzle on l, then stores 256B row segments of u^T.
// ---------------------------------------------------------------------------
__global__ __launch_bounds__(256)
void gemm_u(const short* __restrict__ A, const short* __restrict__ Bt,
            const float* __restrict__ bias, short* __restrict__ ut)
{
    __shared__ __align__(16) short smem[128 * 128];   // As | Bs, then T
    short* As = smem;
    short* Bs = smem + 128*64;
    const int tid = threadIdx.x;
    const int w = tid >> 6, lane = tid & 63;
    const int m0 = blockIdx.x * 128, n0 = blockIdx.y * 128;
    const int wm = w >> 1, wn = w & 1;
    const int lane15 = lane & 15, lhi = lane >> 4;
    const int K = 512;

    f32x4 acc[4][4];
    #pragma unroll
    for (int i = 0; i < 4; ++i)
        #pragma unroll
        for (int j = 0; j < 4; ++j) acc[i][j] = (f32x4){0.f, 0.f, 0.f, 0.f};

    for (int k0 = 0; k0 < K; k0 += 64) {
        #pragma unroll
        for (int i = 0; i < 4; ++i) {
            int row = 32*w + 8*i + (lane >> 3);
            int kch = (lane & 7) ^ (row & 7);
            gload_lds16(A + (size_t)(m0 + row) * K + k0 + kch*8, &As[(32*w + 8*i) * 64]);
        }
        #pragma unroll
        for (int i = 0; i < 4; ++i) {
            int row = 32*w + 8*i + (lane >> 3);
            int kch = (lane & 7) ^ (row & 7);
            gload_lds16(Bt + (size_t)(n0 + row) * K + k0 + kch*8, &Bs[(32*w + 8*i) * 64]);
        }
        __syncthreads();
        #pragma unroll
        for (int kk = 0; kk < 64; kk += 32) {
            bf16x8 af[4], bfr[4];
            const int kb = kk + lhi * 8;
            #pragma unroll
            for (int mi = 0; mi < 4; ++mi) {
                int row = wm*64 + mi*16 + lane15;
                af[mi] = *(const bf16x8*)&As[(row*64 + kb) ^ ((row & 7) << 3)];
            }
            #pragma unroll
            for (int ni = 0; ni < 4; ++ni) {
                int row = wn*64 + ni*16 + lane15;
                bfr[ni] = *(const bf16x8*)&Bs[(row*64 + kb) ^ ((row & 7) << 3)];
            }
            #pragma unroll
            for (int mi = 0; mi < 4; ++mi)
                #pragma unroll
                for (int ni = 0; ni < 4; ++ni)
                    acc[mi][ni] = __builtin_amdgcn_mfma_f32_16x16x32_bf16(
                        af[mi], bfr[ni], acc[mi][ni], 0, 0, 0);
        }
        __syncthreads();
    }
    // T[h][l]: index = h*128 + (l ^ ((h&7)<<3))
    #pragma unroll
    for (int mi = 0; mi < 4; ++mi) {
        #pragma unroll
        for (int ni = 0; ni < 4; ++ni) {
            int hcol = wn*64 + ni*16 + lane15;
            float bv = bias[n0 + hcol];
            #pragma unroll
            for (int r = 0; r < 4; ++r) {
                int bl = wm*64 + mi*16 + lhi*4 + r;
                smem[hcol*128 + (bl ^ ((hcol & 7) << 3))] = f2bf(acc[mi][ni][r] + bv);
            }
        }
    }
    __syncthreads();
    const int b = m0 >> 12, l0 = m0 & 4095;
    #pragma unroll
    for (int p = 0; p < 8; ++p) {
        int hh = p*16 + (tid >> 4);
        int lbase = (tid & 15) * 8;
        bf16x8 v = *(const bf16x8*)&smem[hh*128 + (lbase ^ ((hh & 7) << 3))];
        *(bf16x8*)(ut + ((size_t)(b*512 + n0 + hh))*4096 + l0 + lbase) = v;
    }
}

// ---------------------------------------------------------------------------
// Filter MLP: writes filt_t[h][l] f32 (512 x 4096)
// ---------------------------------------------------------------------------
__global__ __launch_bounds__(256)
void mlp_kernel(const float* __restrict__ fw1, const float* __restrict__ fb1,
                const float* __restrict__ fw2, const float* __restrict__ fb2,
                const float* __restrict__ fw3, const float* __restrict__ fb3,
                float* __restrict__ filt_t)
{
    __shared__ float F1[64][65];
    __shared__ float F2[64][65];
    __shared__ float FO[64][129];
    const int lt = blockIdx.x, ns = blockIdx.y;
    const int l0 = lt * 64, nb = ns * 128;
    const int tid = threadIdx.x;
    for (int i = tid; i < 4096; i += 256) {
        int l = i >> 6, j = i & 63;
        float tv = (float)(l0 + l) * (1.0f / 4095.0f);
        F1[l][j] = gelu_exact(tv * fw1[j] + fb1[j]);
    }
    __syncthreads();
    {
        int j = tid & 63, lb = tid >> 6;
        for (int li = 0; li < 16; ++li) {
            int l = lb*16 + li;
            float sum = fb2[j];
            #pragma unroll
            for (int k = 0; k < 64; ++k) sum += F1[l][k] * fw2[k*64 + j];
            F2[l][j] = gelu_exact(sum);
        }
    }
    __syncthreads();
    {
        const int nn = tid & 127;
        const int lofs = tid >> 7;
        for (int jj = 0; jj < 32; ++jj) {
            int l = lofs + 2*jj;
            float sum = fb3[nb + nn];
            #pragma unroll
            for (int k = 0; k < 64; ++k) sum += F2[l][k] * fw3[k*512 + nb + nn];
            FO[l][nn] = sum;
        }
    }
    __syncthreads();
    for (int i = tid; i < 8192; i += 256) {
        int nn = i >> 6, l = i & 63;
        filt_t[(size_t)(nb + nn) * 4096 + l0 + l] = FO[l][nn];
    }
}

// ---------------------------------------------------------------------------
// Radix-4 FFT (4096 pts), in-LDS. Padding i + (i>>2) (pad every 4 elements)
// kills the q=4-stage 4-way bank conflicts of the previous i + (i>>4) layout
// (verified per-stage: q in {1,4,64,256,1024} conflict-free, q=16 2-way max).
// MODE 0: real f32 filt row -> spectrum (digit-reversed) to Fout.
// MODE 1: load u^T bf16 (2 batches packed re/im), depthwise conv3 in LDS,
//         fwd FFT, multiply by Fh (fused in inverse stage 0), inverse,
//         write filtered bf16 (in place over u^T).
// ---------------------------------------------------------------------------
#define FIDX(i) ((i) + ((i) >> 2))

template<int MODE>
__global__ __launch_bounds__(256)
void fft_kernel(const float* __restrict__ rin_f, const short* __restrict__ rin_h,
                const float2* __restrict__ Fh, short* __restrict__ rout_h,
                float2* __restrict__ Fout, const float2* __restrict__ tw,
                const float* __restrict__ cw3, const float* __restrict__ cbv)
{
    __shared__ float2 S[4096 + 1024];
    const int tid = threadIdx.x;
    const int hh = blockIdx.x;
    if (MODE == 0) {
        const float* src = rin_f + (size_t)hh * 4096;
        for (int i = tid; i < 4096; i += 256) S[FIDX(i)] = make_float2(src[i], 0.f);
        __syncthreads();
    } else {
        const int b0 = blockIdx.y * 2, b1 = b0 + 1;
        const short* s0 = rin_h + ((size_t)b0 * 512 + hh) * 4096;
        const short* s1 = rin_h + ((size_t)b1 * 512 + hh) * 4096;
        for (int i = tid; i < 4096; i += 256)
            S[FIDX(i)] = make_float2(bf2f(s0[i]), bf2f(s1[i]));
        __syncthreads();
        // depthwise conv3, pad=1 (applies to both packed batches)
        const float c0 = cw3[hh*3 + 0], c1 = cw3[hh*3 + 1], c2 = cw3[hh*3 + 2];
        const float cb = cbv[hh];
        float2 r[16];
        #pragma unroll
        for (int k = 0; k < 16; ++k) {
            int i = tid + 256*k;
            float2 um = (i == 0)    ? make_float2(0.f, 0.f) : S[FIDX(i-1)];
            float2 uc = S[FIDX(i)];
            float2 up = (i == 4095) ? make_float2(0.f, 0.f) : S[FIDX(i+1)];
            r[k] = make_float2(um.x*c0 + uc.x*c1 + up.x*c2 + cb,
                               um.y*c0 + uc.y*c1 + up.y*c2 + cb);
        }
        __syncthreads();
        #pragma unroll
        for (int k = 0; k < 16; ++k) S[FIDX(tid + 256*k)] = r[k];
        __syncthreads();
    }
    // forward DIF radix-4: natural in -> digit-reversed out
    #pragma unroll
    for (int s = 0; s < 6; ++s) {
        const int lq = 10 - 2*s;
        const int q = 1 << lq;
        const int tf = 1 << (2*s);
        for (int bfy = tid; bfy < 1024; bfy += 256) {
            const int j = bfy & (q - 1);
            const int base = ((bfy >> lq) << (lq + 2)) + j;
            float2 a = S[FIDX(base)];
            float2 b = S[FIDX(base + q)];
            float2 c = S[FIDX(base + 2*q)];
            float2 d = S[FIDX(base + 3*q)];
            float2 t0 = make_float2(a.x + c.x, a.y + c.y);
            float2 t1 = make_float2(a.x - c.x, a.y - c.y);
            float2 t2 = make_float2(b.x + d.x, b.y + d.y);
            float2 t3 = make_float2(b.x - d.x, b.y - d.y);
            float2 o0 = make_float2(t0.x + t2.x, t0.y + t2.y);
            float2 p1 = make_float2(t1.x + t3.y, t1.y - t3.x);   // t1 - i*t3
            float2 p2 = make_float2(t0.x - t2.x, t0.y - t2.y);
            float2 p3 = make_float2(t1.x - t3.y, t1.y + t3.x);   // t1 + i*t3
            S[FIDX(base)]       = o0;
            S[FIDX(base + q)]   = cmul(p1, tw[j * tf]);
            S[FIDX(base + 2*q)] = cmul(p2, tw[2 * j * tf]);
            S[FIDX(base + 3*q)] = cmul(p3, tw[3 * j * tf]);
        }
        __syncthreads();
    }
    if (MODE == 0) {
        float2* dst = Fout + (size_t)hh * 4096;
        for (int i = tid; i < 4096; i += 256) dst[i] = S[FIDX(i)];
        return;
    }
    // inverse stages (exact algebraic inverse), spectrum multiply fused at s=0
    const float2* F = Fh + (size_t)hh * 4096;
    #pragma unroll
    for (int s = 0; s < 6; ++s) {
        const int q = 1 << (2*s);
        const int tf = 1 << (10 - 2*s);
        for (int bfy = tid; bfy < 1024; bfy += 256) {
            const int j = bfy & (q - 1);
            const int base = ((bfy >> (2*s)) << (2*s + 2)) + j;
            float2 u0 = S[FIDX(base)];
            float2 u1 = S[FIDX(base + q)];
            float2 u2 = S[FIDX(base + 2*q)];
            float2 u3 = S[FIDX(base + 3*q)];
            if (s == 0) {
                u0 = cmul(u0, F[base]);     u1 = cmul(u1, F[base + 1]);
                u2 = cmul(u2, F[base + 2]); u3 = cmul(u3, F[base + 3]);
            } else {
                u1 = cmulc(u1, tw[j * tf]);
                u2 = cmulc(u2, tw[2 * j * tf]);
                u3 = cmulc(u3, tw[3 * j * tf]);
            }
            float2 pp = make_float2(u0.x + u2.x, u0.y + u2.y);
            float2 mm = make_float2(u0.x - u2.x, u0.y - u2.y);
            float2 rr = make_float2(u1.x + u3.x, u1.y + u3.y);
            float2 tt = make_float2(u1.x - u3.x, u1.y - u3.y);
            S[FIDX(base)]       = make_float2(pp.x + rr.x, pp.y + rr.y);
            S[FIDX(base + q)]   = make_float2(mm.x - tt.y, mm.y + tt.x);
            S[FIDX(base + 2*q)] = make_float2(pp.x - rr.x, pp.y - rr.y);
            S[FIDX(base + 3*q)] = make_float2(mm.x + tt.y, mm.y - tt.x);
        }
        __syncthreads();
    }
    const int b0 = blockIdx.y * 2, b1 = b0 + 1;
    short* d0 = rout_h + ((size_t)b0 * 512 + hh) * 4096;
    short* d1 = rout_h + ((size_t)b1 * 512 + hh) * 4096;
    const float inv = 1.0f / 4096.0f;
    for (int i = tid; i < 4096; i += 256) {
        float2 v = S[FIDX(i)];
        d0[i] = f2bf(v.x * inv);
        d1[i] = f2bf(v.y * inv);
    }
}

// ---------------------------------------------------------------------------
// Gate: gated = v * filtered * sigmoid(z); transpose ft (B,H,L)->(B,L,H)
// ---------------------------------------------------------------------------
__global__ __launch_bounds__(256)
void gateT_kernel(const short* __restrict__ ft, const short* __restrict__ v,
                  const short* __restrict__ z, short* __restrict__ gated)
{
    __shared__ float Fd[64][65];
    const int lt = blockIdx.x, ht = blockIdx.y, b = blockIdx.z;
    const int l0 = lt * 64, h0 = ht * 64;
    const int tid = threadIdx.x, c63 = tid & 63, r4 = tid >> 6;
    for (int j = 0; j < 16; ++j) {
        int hh = r4 + 4*j;
        Fd[hh][c63] = bf2f(ft[((size_t)(b*512 + h0 + hh)) * 4096 + l0 + c63]);
    }
    __syncthreads();
    for (int j = 0; j < 16; ++j) {
        int l = l0 + r4 + 4*j;
        size_t row = (size_t)(b*4096 + l) * 512;
        float vv = bf2f(v[row + h0 + c63]);
        float zz = bf2f(z[row + h0 + c63]);
        float f = Fd[c63][r4 + 4*j];
        gated[row + h0 + c63] = f2bf(vv * f * sigmoidf_(zz));
    }
}

// ---------------------------------------------------------------------------
// Weight transpose + f32->bf16: in [R][C] -> out [C][R], z = depth slice
// ---------------------------------------------------------------------------
__global__ __launch_bounds__(256)
void transpose_cvt(const float* __restrict__ in, short* __restrict__ out, int R, int C)
{
    __shared__ float T[32][33];
    const size_t off = (size_t)blockIdx.z * R * C;
    const float* ip = in + off;
    short* op = out + off;
    int tx = threadIdx.x & 31, ty = threadIdx.x >> 5;
    int r0 = blockIdx.y * 32, c0 = blockIdx.x * 32;
    for (int j = 0; j < 4; ++j)
        T[ty + 8*j][tx] = ip[(size_t)(r0 + ty + 8*j) * C + c0 + tx];
    __syncthreads();
    for (int j = 0; j < 4; ++j)
        op[(size_t)(c0 + ty + 8*j) * R + r0 + tx] = f2bf(T[tx][ty + 8*j]);
}

__global__ void twiddle_kernel(float2* tw)
{
    int k = blockIdx.x * 256 + threadIdx.x;
    if (k < 4096) {
        float ang = -(float)(6.283185307179586 / 4096.0) * (float)k;
        tw[k] = make_float2(cosf(ang), sinf(ang));
    }
}

// ---------------------------------------------------------------------------
// Head: out[m][0..1] = g2[m]@hw2 + hb2 (one wave per row)
// ---------------------------------------------------------------------------
__global__ __launch_bounds__(256)
void head_kernel(const short* __restrict__ g2, const float* __restrict__ hw2,
                 const float* __restrict__ hb2, float* __restrict__ out)
{
    const int m = blockIdx.x * 4 + (threadIdx.x >> 6);
    const int lane = threadIdx.x & 63;
    const short* row = g2 + (size_t)m * 256;
    float a0 = 0.f, a1 = 0.f;
    #pragma unroll
    for (int i = 0; i < 4; ++i) {
        int k = lane*4 + i;
        float gv = bf2f(row[k]);
        a0 += gv * hw2[2*k];
        a1 += gv * hw2[2*k + 1];
    }
    #pragma unroll
    for (int o = 32; o > 0; o >>= 1) { a0 += __shfl_xor(a0, o); a1 += __shfl_xor(a1, o); }
    if (lane == 0) {
        out[(size_t)m*2]     = a0 + hb2[0];
        out[(size_t)m*2 + 1] = a1 + hb2[1];
    }
}

// ---------------------------------------------------------------------------
extern "C" void kernel_launch(void* const* d_in, const int* in_sizes, int n_in,
                              void* d_out, int out_size, void* d_ws, size_t ws_size,
                              hipStream_t stream)
{
    const float* x      = (const float*)d_in[0];
    const int*   eids   = (const int*)d_in[1];
    const float* in_w   = (const float*)d_in[2];
    const float* in_b   = (const float*)d_in[3];
    const float* eemb   = (const float*)d_in[4];
    const float* ln_g   = (const float*)d_in[5];
    const float* ln_b   = (const float*)d_in[6];
    const float* fw1    = (const float*)d_in[7];
    const float* fb1    = (const float*)d_in[8];
    const float* fw2    = (const float*)d_in[9];
    const float* fb2    = (const float*)d_in[10];
    const float* fw3    = (const float*)d_in[11];
    const float* fb3    = (const float*)d_in[12];
    const float* cw     = (const float*)d_in[13];
    const float* cb     = (const float*)d_in[14];
    const float* win_w  = (const float*)d_in[15];
    const float* win_b  = (const float*)d_in[16];
    const float* wout_w = (const float*)d_in[17];
    const float* wout_b = (const float*)d_in[18];
    const float* fln_g  = (const float*)d_in[19];
    const float* fln_b  = (const float*)d_in[20];
    const float* hw1    = (const float*)d_in[21];
    const float* hb1    = (const float*)d_in[22];
    const float* hw2    = (const float*)d_in[23];
    const float* hb2    = (const float*)d_in[24];
    float* out = (float*)d_out;

    // ---- workspace layout (~225 MB) ----
    char* p = (char*)d_ws;
    auto alloc = [&](size_t bytes) { char* r = p; p += (bytes + 255) & ~(size_t)255; return r; };
    float2* tw     = (float2*)alloc((size_t)4096 * sizeof(float2));          // 32 KB
    short*  winT8  = (short*)alloc((size_t)8 * 1536 * 512 * 2);              // 12.6 MB
    short*  woutT8 = (short*)alloc((size_t)8 * 512 * 512 * 2);               // 4.2 MB
    short*  hw1T   = (short*)alloc((size_t)256 * 512 * 2);                   // 0.26 MB
    float*  h      = (float*)alloc((size_t)32768 * 512 * 4);                 // 64 MB
    short*  hn     = (short*)alloc((size_t)32768 * 512 * 2);                 // 32 MB (also: gated)
    short*  v      = (short*)alloc((size_t)32768 * 512 * 2);                 // 32 MB (also: head g2)
    short*  z      = (short*)alloc((size_t)32768 * 512 * 2);                 // 32 MB (also: delta)
    short*  ut     = (short*)alloc((size_t)8 * 512 * 4096 * 2);              // 32 MB u^T / filtered
    float*  filt   = (float*)ut;   // overlay: filt (8 MB f32) dead before gemm_u writes ut
    float2* Fh     = (float2*)alloc((size_t)512 * 4096 * sizeof(float2));    // 16 MB

    twiddle_kernel<<<16, 256, 0, stream>>>(tw);
    transpose_cvt<<<dim3(48, 16, 8), 256, 0, stream>>>(win_w, winT8, 512, 1536);
    transpose_cvt<<<dim3(16, 16, 8), 256, 0, stream>>>(wout_w, woutT8, 512, 512);
    transpose_cvt<<<dim3(8, 16, 1), 256, 0, stream>>>(hw1, hw1T, 512, 256);
    embed_kernel<<<32768, 256, 0, stream>>>(x, eids, in_w, in_b, eemb, h);

    for (int d = 0; d < 8; ++d) {
        const short* winTd = winT8 + (size_t)d * 1536 * 512;
        mlp_kernel<<<dim3(64, 4), 256, 0, stream>>>(
            fw1 + d*64, fb1 + d*64, fw2 + (size_t)d*64*64, fb2 + d*64,
            fw3 + (size_t)d*64*512, fb3 + d*512, filt);
        fft_kernel<0><<<512, 256, 0, stream>>>(
            filt, nullptr, nullptr, nullptr, Fh, tw, nullptr, nullptr);
        // LN with fused residual add of the previous depth's delta (in z)
        ln_kernel<<<8192, 256, 0, stream>>>(
            h, (d == 0) ? nullptr : z, ln_g + d*512, ln_b + d*512, hn);
        gemm_u<<<dim3(256, 4), 256, 0, stream>>>(
            hn, winTd + (size_t)512*512, win_b + d*1536 + 512, ut);
        gemm_vz_split<<<dim3(256, 8), 256, 0, stream>>>(
            hn, winTd, win_b + d*1536, v, z);
        fft_kernel<1><<<dim3(512, 4), 256, 0, stream>>>(
            nullptr, ut, Fh, ut, nullptr, tw, cw + (size_t)d*512*3, cb + d*512);
        gateT_kernel<<<dim3(64, 8, 8), 256, 0, stream>>>(ut, v, z, hn);
        // writes bf16 delta into z (dead after gateT); consumed by next LN
        gemm_bf16<0><<<dim3(256, 4), 256, 0, stream>>>(
            hn, woutT8 + (size_t)d*512*512, wout_b + d*512, z, 512, 512);
    }

    ln_kernel<<<8192, 256, 0, stream>>>(h, z, fln_g, fln_b, hn);
    gemm_bf16<2><<<dim3(256, 2), 256, 0, stream>>>(
        hn, hw1T, hb1, (short*)v, 256, 512);
    head_kernel<<<8192, 256, 0, stream>>>((short*)v, hw2, hb2, out);
}